// Round 10
// baseline (497.910 us; speedup 1.0000x reference)
//
#include <hip/hip_runtime.h>

typedef float f32x4 __attribute__((ext_vector_type(4)));
typedef short s16x8 __attribute__((ext_vector_type(8)));

constexpr int L = 2048;
constexpr int V = 2048;
constexpr int NB = 4;
constexpr size_t VV  = (size_t)V * V;      // 4194304
constexpr size_t BLV = (size_t)NB * L * V; // 16777216
constexpr size_t LV  = (size_t)L * V;      // 4194304

// ---------- bf16 helpers (bit-level, RNE) ----------
__device__ __forceinline__ unsigned short f2bf(float f) {
    unsigned u = __float_as_uint(f);
    u = (u + 0x7FFFu + ((u >> 16) & 1u)) >> 16;
    return (unsigned short)u;
}
__device__ __forceinline__ float bf2f(unsigned short s) {
    return __uint_as_float(((unsigned)s) << 16);
}

// ---------- async global->LDS 16B ----------
__device__ __forceinline__ void gload16(const unsigned short* g, unsigned short* l) {
    auto gp = (const __attribute__((address_space(1))) unsigned int*)g;
    auto lp = (__attribute__((address_space(3))) unsigned int*)l;
    __builtin_amdgcn_global_load_lds(gp, lp, 16, 0, 0);
}

#define SBAR __builtin_amdgcn_sched_barrier(0)

// ================= 256x256 bf16 8-phase pipelined GEMM machinery =================
// BK=64 K-tiles, 2 LDS buffers x 64KB. Buffer layout (shorts):
//   A-Ks0 @0, A-Ks1 @8192, B-Ks0 @16384, B-Ks1 @24576  (each 256 rows x 32 shorts)
// Swizzle within slice: 16B slot = kc ^ (row&3). Stage = pre-swizzled global src +
// linear global_load_lds (2 loads/thread per half). 4 phases/K-tile, 16 MFMA each;
// one half staged per phase into the non-read buffer; vmcnt(4) at ph1/ph3 ends.

// stage one K-slice half (256x32 shorts) of matrix G into LDS slice base
__device__ __forceinline__ void stage_half(const unsigned short* G, int r0, int k0, int s,
                                           unsigned short* slice, int wave, int lane) {
    int rl = lane >> 2, slot = lane & 3;
    #pragma unroll
    for (int r = 0; r < 2; ++r) {
        int rowl = r * 128 + wave * 16 + rl;
        int colg = k0 + s * 32 + ((slot ^ (rowl & 3)) * 8);
        gload16(G + (size_t)(r0 + rowl) * 2048 + colg,
                slice + (size_t)(r * 128 + wave * 16) * 32);
    }
}

__device__ __forceinline__ s16x8 frag64(const unsigned short* slice, int row, int kc) {
    return *(const s16x8*)&slice[row * 32 + ((kc ^ (row & 3)) * 8)];
}

__device__ __forceinline__ void kloop64(const unsigned short* Ab, const unsigned short* Bb,
                                        int m0, int n0, int NT, unsigned short* lds,
                                        int wave, int lane, int wr, int wc,
                                        f32x4 (&acc)[8][4]) {
    const int r15 = lane & 15, kc = lane >> 4;

    // prologue: tile0's 4 halves in issue order A-Ks0, B-Ks0, A-Ks1, B-Ks1
    stage_half(Ab, m0, 0, 0, lds + 0,     wave, lane);
    stage_half(Bb, n0, 0, 0, lds + 16384, wave, lane);
    stage_half(Ab, m0, 0, 1, lds + 8192,  wave, lane);
    stage_half(Bb, n0, 0, 1, lds + 24576, wave, lane);
    asm volatile("s_waitcnt vmcnt(4)" ::: "memory");
    SBAR; __builtin_amdgcn_s_barrier(); SBAR;

    for (int t = 0; t < NT; ++t) {
        unsigned short* cur = lds + (t & 1) * 32768;
        unsigned short* nxt = lds + ((t + 1) & 1) * 32768;
        const bool pre = (t + 1 < NT);
        const int k1 = (t + 1) * 64;

        s16x8 b0[4], b1[4], a[4];

        // ---------- ph0: Ks0, acc[0-3] ----------
        #pragma unroll
        for (int nf = 0; nf < 4; ++nf)
            b0[nf] = frag64(cur + 16384, wc * 64 + nf * 16 + r15, kc);
        #pragma unroll
        for (int mf = 0; mf < 4; ++mf)
            a[mf] = frag64(cur, wr * 128 + mf * 16 + r15, kc);
        if (pre) stage_half(Ab, m0, k1, 0, nxt, wave, lane);
        SBAR; __builtin_amdgcn_s_barrier(); SBAR;
        __builtin_amdgcn_s_setprio(1);
        #pragma unroll
        for (int mf = 0; mf < 4; ++mf)
            #pragma unroll
            for (int nf = 0; nf < 4; ++nf)
                acc[mf][nf] = __builtin_amdgcn_mfma_f32_16x16x32_bf16(a[mf], b0[nf], acc[mf][nf], 0, 0, 0);
        __builtin_amdgcn_s_setprio(0);
        SBAR; __builtin_amdgcn_s_barrier(); SBAR;

        // ---------- ph1: Ks0, acc[4-7] ----------
        #pragma unroll
        for (int mf = 0; mf < 4; ++mf)
            a[mf] = frag64(cur, wr * 128 + (mf + 4) * 16 + r15, kc);
        if (pre) stage_half(Bb, n0, k1, 0, nxt + 16384, wave, lane);
        SBAR; __builtin_amdgcn_s_barrier(); SBAR;
        __builtin_amdgcn_s_setprio(1);
        #pragma unroll
        for (int mf = 0; mf < 4; ++mf)
            #pragma unroll
            for (int nf = 0; nf < 4; ++nf)
                acc[mf + 4][nf] = __builtin_amdgcn_mfma_f32_16x16x32_bf16(a[mf], b0[nf], acc[mf + 4][nf], 0, 0, 0);
        __builtin_amdgcn_s_setprio(0);
        SBAR;
        if (pre) { asm volatile("s_waitcnt vmcnt(4)" ::: "memory"); }
        else     { asm volatile("s_waitcnt vmcnt(0)" ::: "memory"); }
        SBAR; __builtin_amdgcn_s_barrier(); SBAR;

        // ---------- ph2: Ks1, acc[0-3] ----------
        #pragma unroll
        for (int nf = 0; nf < 4; ++nf)
            b1[nf] = frag64(cur + 24576, wc * 64 + nf * 16 + r15, kc);
        #pragma unroll
        for (int mf = 0; mf < 4; ++mf)
            a[mf] = frag64(cur + 8192, wr * 128 + mf * 16 + r15, kc);
        if (pre) stage_half(Ab, m0, k1, 1, nxt + 8192, wave, lane);
        SBAR; __builtin_amdgcn_s_barrier(); SBAR;
        __builtin_amdgcn_s_setprio(1);
        #pragma unroll
        for (int mf = 0; mf < 4; ++mf)
            #pragma unroll
            for (int nf = 0; nf < 4; ++nf)
                acc[mf][nf] = __builtin_amdgcn_mfma_f32_16x16x32_bf16(a[mf], b1[nf], acc[mf][nf], 0, 0, 0);
        __builtin_amdgcn_s_setprio(0);
        SBAR; __builtin_amdgcn_s_barrier(); SBAR;

        // ---------- ph3: Ks1, acc[4-7] ----------
        #pragma unroll
        for (int mf = 0; mf < 4; ++mf)
            a[mf] = frag64(cur + 8192, wr * 128 + (mf + 4) * 16 + r15, kc);
        if (pre) stage_half(Bb, n0, k1, 1, nxt + 24576, wave, lane);
        SBAR; __builtin_amdgcn_s_barrier(); SBAR;
        __builtin_amdgcn_s_setprio(1);
        #pragma unroll
        for (int mf = 0; mf < 4; ++mf)
            #pragma unroll
            for (int nf = 0; nf < 4; ++nf)
                acc[mf + 4][nf] = __builtin_amdgcn_mfma_f32_16x16x32_bf16(a[mf], b1[nf], acc[mf + 4][nf], 0, 0, 0);
        __builtin_amdgcn_s_setprio(0);
        SBAR;
        if (pre) { asm volatile("s_waitcnt vmcnt(4)" ::: "memory"); }
        SBAR; __builtin_amdgcn_s_barrier(); SBAR;
    }
}

// ---------------- data GEMM (batched; TOEP variant) ----------------
template<int OUTM, bool TOEP>      // OUTM: 0 = f32 out, 1 = bf16 out
__global__ __launch_bounds__(512, 2) void gemm_big(
    const unsigned short* __restrict__ A, size_t sA,
    const unsigned short* __restrict__ B, size_t sB,
    float* __restrict__ outF, unsigned short* __restrict__ outH, size_t sO,
    const int* __restrict__ idxp, const float* __restrict__ ks)
{
    __shared__ __align__(16) unsigned short lds[2 * 32768];

    const int tid  = threadIdx.x;
    const int lane = tid & 63, wave = tid >> 6;
    const int wr = wave >> 2, wc = wave & 3;        // 2 x 4 wave grid
    const int bz = blockIdx.z;
    int bx = blockIdx.x, by = blockIdx.y;
    if constexpr (TOEP) { int tswap = bx; bx = by; by = tswap; }  // causal balance
    const int m0 = by * 256, n0 = bx * 256;
    const int r15 = lane & 15, kc = lane >> 4;

    const unsigned short* Ab = A + (size_t)bz * sA;
    const unsigned short* Bb = B + (size_t)bz * sB;
    const int NT = TOEP ? 4 * (bx + 1) : 32;

    f32x4 acc[8][4];
    const f32x4 zf = {0.f, 0.f, 0.f, 0.f};
    #pragma unroll
    for (int i = 0; i < 8; ++i)
        #pragma unroll
        for (int j = 0; j < 4; ++j) acc[i][j] = zf;

    kloop64(Ab, Bb, m0, n0, NT, lds, wave, lane, wr, wc, acc);

    float csc[4];
    if constexpr (TOEP) {
        #pragma unroll
        for (int nf = 0; nf < 4; ++nf) {
            int gcol = n0 + wc * 64 + nf * 16 + r15;
            csc[nf] = ks[idxp[bz * L + gcol]];
        }
    }
    #pragma unroll
    for (int mf = 0; mf < 8; ++mf) {
        #pragma unroll
        for (int r = 0; r < 4; ++r) {
            int grow = m0 + wr * 128 + mf * 16 + kc * 4 + r;
            #pragma unroll
            for (int nf = 0; nf < 4; ++nf) {
                float v = acc[mf][nf][r];
                if constexpr (TOEP) v *= csc[nf];
                int gcol = n0 + wc * 64 + nf * 16 + r15;
                size_t o = (size_t)bz * sO + (size_t)grow * 2048 + gcol;
                if constexpr (OUTM == 0) outF[o] = v;
                else                     outH[o] = f2bf(v);
            }
        }
    }
}

// ---------------- precompute GEMMs: up to 3 independent [V,V] per launch ----------------
struct PDesc { const unsigned short* A; const unsigned short* B; float* oF; unsigned short* oH; };

__global__ __launch_bounds__(512, 2) void gemm_pre_big(PDesc d0, PDesc d1, PDesc d2) {
    PDesc d = (blockIdx.z == 0) ? d0 : (blockIdx.z == 1) ? d1 : d2;
    __shared__ __align__(16) unsigned short lds[2 * 32768];

    const int tid  = threadIdx.x;
    const int lane = tid & 63, wave = tid >> 6;
    const int wr = wave >> 2, wc = wave & 3;
    const int m0 = blockIdx.y * 256, n0 = blockIdx.x * 256;
    const int r15 = lane & 15, kc = lane >> 4;

    f32x4 acc[8][4];
    const f32x4 zf = {0.f, 0.f, 0.f, 0.f};
    #pragma unroll
    for (int i = 0; i < 8; ++i)
        #pragma unroll
        for (int j = 0; j < 4; ++j) acc[i][j] = zf;

    kloop64(d.A, d.B, m0, n0, 32, lds, wave, lane, wr, wc, acc);

    const bool isF = (d.oF != nullptr);
    #pragma unroll
    for (int mf = 0; mf < 8; ++mf) {
        #pragma unroll
        for (int r = 0; r < 4; ++r) {
            int grow = m0 + wr * 128 + mf * 16 + kc * 4 + r;
            #pragma unroll
            for (int nf = 0; nf < 4; ++nf) {
                float v = acc[mf][nf][r];
                int gcol = n0 + wc * 64 + nf * 16 + r15;
                size_t o = (size_t)grow * 2048 + gcol;
                if (isF) d.oF[o] = v;
                else     d.oH[o] = f2bf(v);
            }
        }
    }
}

// ---- split-K precompute: z-th K=512 chunk of OUT = A . B^Trows -> f32 partial ----
__global__ __launch_bounds__(512, 2) void gemm_preK(const unsigned short* __restrict__ A,
                                                    const unsigned short* __restrict__ B,
                                                    float* __restrict__ outP) {
    __shared__ __align__(16) unsigned short lds[2 * 32768];

    const int tid  = threadIdx.x;
    const int lane = tid & 63, wave = tid >> 6;
    const int wr = wave >> 2, wc = wave & 3;
    const int m0 = blockIdx.y * 256, n0 = blockIdx.x * 256;
    const int r15 = lane & 15, kc = lane >> 4;
    const int z = blockIdx.z;

    const unsigned short* Ab = A + z * 512;
    const unsigned short* Bb = B + z * 512;
    float* outF = outP + (size_t)z * VV;

    f32x4 acc[8][4];
    const f32x4 zf = {0.f, 0.f, 0.f, 0.f};
    #pragma unroll
    for (int i = 0; i < 8; ++i)
        #pragma unroll
        for (int j = 0; j < 4; ++j) acc[i][j] = zf;

    kloop64(Ab, Bb, m0, n0, 8, lds, wave, lane, wr, wc, acc);

    #pragma unroll
    for (int mf = 0; mf < 8; ++mf) {
        #pragma unroll
        for (int r = 0; r < 4; ++r) {
            int grow = m0 + wr * 128 + mf * 16 + kc * 4 + r;
            #pragma unroll
            for (int nf = 0; nf < 4; ++nf) {
                int gcol = n0 + wc * 64 + nf * 16 + r15;
                outF[(size_t)grow * 2048 + gcol] = acc[mf][nf][r];
            }
        }
    }
}

// reduce 4 f32 partials -> bf16
__global__ __launch_bounds__(256) void reduce4_cast(const float* __restrict__ P,
                                                    unsigned short* __restrict__ H) {
    int i = blockIdx.x * 256 + threadIdx.x;          // float4 index, < VV/4
    const float4* p0 = (const float4*)P;
    const float4* p1 = (const float4*)(P + VV);
    const float4* p2 = (const float4*)(P + 2 * VV);
    const float4* p3 = (const float4*)(P + 3 * VV);
    float4 a = p0[i], b = p1[i], c = p2[i], d = p3[i];
    ushort4 h;
    h.x = f2bf(a.x + b.x + c.x + d.x);
    h.y = f2bf(a.y + b.y + c.y + d.y);
    h.z = f2bf(a.z + b.z + c.z + d.z);
    h.w = f2bf(a.w + b.w + c.w + d.w);
    ((ushort4*)H)[i] = h;
}

// ---------------- prep kernels ----------------

__global__ __launch_bounds__(256) void colsum_atomic(const float* __restrict__ W,
                                                     float* __restrict__ out) {
    int r0 = blockIdx.x * 8;
    int c = threadIdx.x;
    float s[8];
    #pragma unroll
    for (int i = 0; i < 8; ++i) s[i] = 0.f;
    for (int r = 0; r < 8; ++r) {
        const float* row = W + (size_t)(r0 + r) * V;
        #pragma unroll
        for (int i = 0; i < 8; ++i) s[i] += row[c + i * 256];
    }
    #pragma unroll
    for (int i = 0; i < 8; ++i) atomicAdd(&out[c + i * 256], s[i]);
}

__global__ void init_kernel(float* __restrict__ ks0, float* __restrict__ ks1) {
    int i = blockIdx.x * 256 + threadIdx.x;
    if (i < 2048) { ks0[i] = 0.f; ks1[i] = 0.f; }
}

// materialize Toeplitz: TB[n][k] = (k<=n) ? v1[n-k] : 0 (bf16); grid 2048 x 256 thr
__global__ __launch_bounds__(256) void tb_fill(const float* __restrict__ v1,
                                               unsigned short* __restrict__ TBh) {
    int n = blockIdx.x;
    int c0 = threadIdx.x * 8;
    s16x8 hv;
    #pragma unroll
    for (int i = 0; i < 8; ++i) {
        int k = c0 + i;
        float f = (k <= n) ? v1[n - k] : 0.f;
        hv[i] = (short)f2bf(f);
    }
    *(s16x8*)&TBh[(size_t)n * 2048 + c0] = hv;
}

struct TDesc { const float* A; unsigned short* Th; };

// 5 fused transpose+cast: Th[i][j] = bf16(A[j][i]); grid (64,64,5), block (32,8)
__global__ void transpose_cast_multi(TDesc d0, TDesc d1, TDesc d2, TDesc d3, TDesc d4) {
    TDesc d;
    switch (blockIdx.z) {
        case 0: d = d0; break;
        case 1: d = d1; break;
        case 2: d = d2; break;
        case 3: d = d3; break;
        default: d = d4; break;
    }
    __shared__ float tile[32][33];
    int x = blockIdx.x * 32 + threadIdx.x;
    int y0 = blockIdx.y * 32;
    for (int r = threadIdx.y; r < 32; r += 8)
        tile[r][threadIdx.x] = d.A[(size_t)(y0 + r) * V + x];
    __syncthreads();
    int xo = blockIdx.y * 32 + threadIdx.x;
    int yo0 = blockIdx.x * 32;
    for (int r = threadIdx.y; r < 32; r += 8)
        d.Th[(size_t)(yo0 + r) * V + xo] = f2bf(tile[threadIdx.x][r]);
}

// plain cast f32 -> bf16
__global__ __launch_bounds__(256) void cast_kernel(const float* __restrict__ A,
                                                   unsigned short* __restrict__ H,
                                                   int n4) {
    int i = blockIdx.x * 256 + threadIdx.x;
    if (i >= n4) return;
    float4 f = ((const float4*)A)[i];
    ushort4 h;
    h.x = f2bf(f.x); h.y = f2bf(f.y); h.z = f2bf(f.z); h.w = f2bf(f.w);
    ((ushort4*)H)[i] = h;
}

// ---------------- scatter kernels (4 q-rows/block, 64 lanes/row, 4x unrolled) ----------------

__global__ __launch_bounds__(256) void scatterA_kernel(const int* __restrict__ idx,
                                                       const float* __restrict__ G0,
                                                       const float* __restrict__ ks0,
                                                       const float* __restrict__ v0,
                                                       unsigned short* __restrict__ Th) {
    __shared__ float buck[4 * 2048];
    int tid = threadIdx.x;
    const float4 z4 = make_float4(0.f, 0.f, 0.f, 0.f);
    #pragma unroll
    for (int i = 0; i < 8; ++i) ((float4*)buck)[tid + i * 256] = z4;
    __syncthreads();

    int b = blockIdx.y, q0 = blockIdx.x * 4;
    int qr = tid >> 6, lane = tid & 63;
    int q = q0 + qr;
    const int* idxb = idx + b * L;
    int iq = idxb[q];
    float kq = ks0[iq];
    const float* Grow = G0 + (size_t)iq * V;
    float* brow = buck + qr * 2048;

    int k = lane;
    for (; k + 192 <= q; k += 256) {
        int i0 = idxb[k], i1 = idxb[k + 64], i2 = idxb[k + 128], i3 = idxb[k + 192];
        float g0 = Grow[i0], g1 = Grow[i1], g2 = Grow[i2], g3 = Grow[i3];
        float w0 = v0[q - k], w1 = v0[q - k - 64], w2 = v0[q - k - 128], w3 = v0[q - k - 192];
        atomicAdd(&brow[i0], g0 + kq * w0);
        atomicAdd(&brow[i1], g1 + kq * w1);
        atomicAdd(&brow[i2], g2 + kq * w2);
        atomicAdd(&brow[i3], g3 + kq * w3);
    }
    for (; k <= q; k += 64) {
        int ik = idxb[k];
        atomicAdd(&brow[ik], Grow[ik] + kq * v0[q - k]);
    }
    __syncthreads();
    size_t base = ((size_t)b * L + q0) * V;
    #pragma unroll
    for (int it = 0; it < 4; ++it) {
        int i = tid + it * 256;                      // s16x8 index < 1024
        s16x8 hv;
        #pragma unroll
        for (int j = 0; j < 8; ++j) hv[j] = (short)f2bf(buck[i * 8 + j]);
        *(s16x8*)&Th[base + (size_t)i * 8] = hv;
    }
}

// T2 is bf16; row reads coalesced
__global__ __launch_bounds__(256) void scatterC_kernel(const int* __restrict__ idx,
                                                       const unsigned short* __restrict__ T2h,
                                                       unsigned short* __restrict__ Th) {
    __shared__ float buck[4 * 2048];
    int tid = threadIdx.x;
    const float4 z4 = make_float4(0.f, 0.f, 0.f, 0.f);
    #pragma unroll
    for (int i = 0; i < 8; ++i) ((float4*)buck)[tid + i * 256] = z4;
    __syncthreads();

    int b = blockIdx.y, q0 = blockIdx.x * 4;
    int qr = tid >> 6, lane = tid & 63;
    int q = q0 + qr;
    const int* idxb = idx + b * L;
    int iq = idxb[q];
    const unsigned short* Trow = T2h + ((size_t)b * V + iq) * L;
    float* brow = buck + qr * 2048;

    int k = lane;
    for (; k + 192 <= q; k += 256) {
        int i0 = idxb[k], i1 = idxb[k + 64], i2 = idxb[k + 128], i3 = idxb[k + 192];
        float t0 = bf2f(Trow[k]), t1 = bf2f(Trow[k + 64]);
        float t2 = bf2f(Trow[k + 128]), t3 = bf2f(Trow[k + 192]);
        atomicAdd(&brow[i0], t0);
        atomicAdd(&brow[i1], t1);
        atomicAdd(&brow[i2], t2);
        atomicAdd(&brow[i3], t3);
    }
    for (; k <= q; k += 64)
        atomicAdd(&brow[idxb[k]], bf2f(Trow[k]));
    __syncthreads();
    size_t base = ((size_t)b * L + q0) * V;
    #pragma unroll
    for (int it = 0; it < 4; ++it) {
        int i = tid + it * 256;
        s16x8 hv;
        #pragma unroll
        for (int j = 0; j < 8; ++j) hv[j] = (short)f2bf(buck[i * 8 + j]);
        *(s16x8*)&Th[base + (size_t)i * 8] = hv;
    }
}

// ---------------- launcher ----------------

extern "C" void kernel_launch(void* const* d_in, const int* in_sizes, int n_in,
                              void* d_out, int out_size, void* d_ws, size_t ws_size,
                              hipStream_t stream) {
    (void)in_sizes; (void)n_in; (void)out_size; (void)ws_size;
    const int*   idx = (const int*)d_in[0];
    const float* Wq0 = (const float*)d_in[1];
    const float* Wk0 = (const float*)d_in[2];
    const float* Wv0 = (const float*)d_in[3];
    const float* Wk1 = (const float*)d_in[4];
    const float* Wv1 = (const float*)d_in[5];
    const float* Wq2 = (const float*)d_in[6];
    const float* Wk2 = (const float*)d_in[7];
    const float* Wv2 = (const float*)d_in[8];
    const float* v0  = (const float*)d_in[9];
    const float* v1  = (const float*)d_in[10];
    float* out = (float*)d_out;

    char* W = (char*)d_ws;
    const size_t MiB = 1024 * 1024;

    // [0, 64 MiB): PPT (8 MiB) early -> TAh (32 MiB) -> T2h (32 MiB)
    unsigned short* PPT = (unsigned short*)W;
    unsigned short* TAh = (unsigned short*)W;
    unsigned short* T2h = (unsigned short*)W;
    // [8, 72 MiB): R split-K f32 partials (64 MiB, live only between pre1 and reduce)
    float* Rp = (float*)(W + 8 * MiB);
    // [64, 96 MiB): Y1 (Wv0T) + Y2 (Wv1 bf16) early -> Uh -> TCh
    unsigned short* Y1 = (unsigned short*)(W + 64 * MiB);
    unsigned short* Y2 = (unsigned short*)(W + 72 * MiB);
    unsigned short* Uh  = (unsigned short*)(W + 64 * MiB);
    unsigned short* TCh = Uh;
    // [96, 112 MiB): G0 f32
    float* Gf = (float*)(W + 96 * MiB);
    // [112, 120): Y4 = M bf16
    unsigned short* Y4 = (unsigned short*)(W + 112 * MiB);
    // [128+): X slots, 8 MiB each (bf16 [V,V])
    unsigned short* X1 = (unsigned short*)(W + 128 * MiB);  // Wq0T, then R bf16
    unsigned short* X2 = (unsigned short*)(W + 136 * MiB);  // Wk0T, then Wv2 bf16
    unsigned short* X3 = (unsigned short*)(W + 144 * MiB);  // Wq2T, then TBh
    unsigned short* X4 = (unsigned short*)(W + 152 * MiB);  // Wk2T
    unsigned short* TBh = X3;
    float* ks0 = (float*)(W + 192 * MiB);
    float* ks1 = (float*)(W + 192 * MiB + 16 * 1024);

    dim3 blk(256);

    // prep: transposes/casts, column sums
    {
        TDesc t0{Wq0, X1}, t1{Wk0, X2}, t2{Wq2, X3}, t3{Wk2, X4}, t4{Wv0, Y1};
        transpose_cast_multi<<<dim3(64, 64, 5), dim3(32, 8), 0, stream>>>(t0, t1, t2, t3, t4);
    }
    cast_kernel<<<dim3((int)(VV / 4 / 256)), blk, 0, stream>>>(Wv1, Y2, (int)(VV / 4));
    init_kernel<<<dim3(8), blk, 0, stream>>>(ks0, ks1);
    colsum_atomic<<<dim3(256), blk, 0, stream>>>(Wk0, ks0);
    colsum_atomic<<<dim3(256), blk, 0, stream>>>(Wk1, ks1);

    // fused precomputes: G0 = Wq0^T Wk0 (f32), M = Wq2^T Wk2 (bf16), PPT (bf16)
    {
        PDesc dG{X1, X2, Gf, nullptr};
        PDesc dM{X3, X4, nullptr, Y4};
        PDesc dP{Y1, Y2, nullptr, PPT};
        gemm_pre_big<<<dim3(8, 8, 3), dim3(512), 0, stream>>>(dG, dM, dP);
    }
    // TB materialization (X3's Wq2T dead after pre)
    tb_fill<<<dim3(2048), blk, 0, stream>>>(v1, TBh);
    // R = M . PPT via split-K (4 x K=512 f32 partials) -> reduce to X1 bf16
    gemm_preK<<<dim3(8, 8, 4), dim3(512), 0, stream>>>(Y4, PPT, Rp);
    reduce4_cast<<<dim3((int)(VV / 4 / 256)), blk, 0, stream>>>(Rp, X1);

    // scatter A -> TAh (overwrites PPT/Rp head; both dead)
    scatterA_kernel<<<dim3(L / 4, NB), blk, 0, stream>>>(idx, Gf, ks0, v0, TAh);

    // U[b] = R . TA[b]^T -> bf16 Uh
    gemm_big<1, false><<<dim3(8, 8, NB), dim3(512), 0, stream>>>(
        X1, 0, TAh, LV, nullptr, Uh, LV, nullptr, nullptr);

    // T2[b][v,q] = ks1[iq_q] * sum_{k<=q} v1[q-k] * U[b][v,k] -> bf16 T2h (TAh dead)
    gemm_big<1, true><<<dim3(8, 8, NB), dim3(512), 0, stream>>>(
        Uh, LV, TBh, 0, nullptr, T2h, LV, idx, ks1);

    // scatter C -> TCh (overwrites Uh; Uh dead after TOEP)
    scatterC_kernel<<<dim3(L / 4, NB), blk, 0, stream>>>(idx, T2h, TCh);

    // Wv2 -> bf16 X2 (Wk0T dead after pre)
    cast_kernel<<<dim3((int)(VV / 4 / 256)), blk, 0, stream>>>(Wv2, X2, (int)(VV / 4));

    // logits = TC . Wv2rows -> d_out (M = 8192)
    gemm_big<0, false><<<dim3(8, 32, 1), dim3(512), 0, stream>>>(
        TCh, 0, X2, 0, out, nullptr, 0, nullptr, nullptr);
}

// Round 11
// 481.579 us; speedup vs baseline: 1.0339x; 1.0339x over previous
//
#include <hip/hip_runtime.h>

typedef float f32x4 __attribute__((ext_vector_type(4)));
typedef short s16x8 __attribute__((ext_vector_type(8)));

constexpr int L = 2048;
constexpr int V = 2048;
constexpr int NB = 4;
constexpr size_t VV  = (size_t)V * V;      // 4194304
constexpr size_t BLV = (size_t)NB * L * V; // 16777216
constexpr size_t LV  = (size_t)L * V;      // 4194304

// ---------- bf16 helpers (bit-level, RNE) ----------
__device__ __forceinline__ unsigned short f2bf(float f) {
    unsigned u = __float_as_uint(f);
    u = (u + 0x7FFFu + ((u >> 16) & 1u)) >> 16;
    return (unsigned short)u;
}
__device__ __forceinline__ float bf2f(unsigned short s) {
    return __uint_as_float(((unsigned)s) << 16);
}

// ---------- async global->LDS 16B ----------
__device__ __forceinline__ void gload16(const unsigned short* g, unsigned short* l) {
    auto gp = (const __attribute__((address_space(1))) unsigned int*)g;
    auto lp = (__attribute__((address_space(3))) unsigned int*)l;
    __builtin_amdgcn_global_load_lds(gp, lp, 16, 0, 0);
}

#define SBAR __builtin_amdgcn_sched_barrier(0)

// ================= 256x256 bf16 8-phase pipelined GEMM machinery =================
// BK=64 K-tiles, 2 LDS buffers x 64KB. Buffer layout (shorts):
//   A-Ks0 @0, A-Ks1 @8192, B-Ks0 @16384, B-Ks1 @24576  (each 256 rows x 32 shorts)
// Swizzle within slice: 16B slot = kc ^ ((row>>1)&3)  [proven conflict-free, r6-r9].
// Stage = pre-swizzled global src + linear global_load_lds (2 loads/thread/half).
// 4 phases/K-tile, 16 MFMA each; one half staged per phase into the non-read
// buffer; counted vmcnt(4) at ph1/ph3 ends (never drained mid-loop).

// stage one K-slice half (256x32 shorts) of matrix G into LDS slice base
__device__ __forceinline__ void stage_half(const unsigned short* G, int r0, int k0, int s,
                                           unsigned short* slice, int wave, int lane) {
    int rl = lane >> 2, slot = lane & 3;
    #pragma unroll
    for (int r = 0; r < 2; ++r) {
        int rowl = r * 128 + wave * 16 + rl;
        int colg = k0 + s * 32 + ((slot ^ ((rowl >> 1) & 3)) * 8);
        gload16(G + (size_t)(r0 + rowl) * 2048 + colg,
                slice + (size_t)(r * 128 + wave * 16) * 32);
    }
}

__device__ __forceinline__ s16x8 frag64(const unsigned short* slice, int row, int kc) {
    return *(const s16x8*)&slice[row * 32 + ((kc ^ ((row >> 1) & 3)) * 8)];
}

__device__ __forceinline__ void kloop64(const unsigned short* Ab, const unsigned short* Bb,
                                        int m0, int n0, int NT, unsigned short* lds,
                                        int wave, int lane, int wr, int wc,
                                        f32x4 (&acc)[8][4]) {
    const int r15 = lane & 15, kc = lane >> 4;

    // prologue: tile0's 4 halves in issue order A-Ks0, B-Ks0, A-Ks1, B-Ks1
    stage_half(Ab, m0, 0, 0, lds + 0,     wave, lane);
    stage_half(Bb, n0, 0, 0, lds + 16384, wave, lane);
    stage_half(Ab, m0, 0, 1, lds + 8192,  wave, lane);
    stage_half(Bb, n0, 0, 1, lds + 24576, wave, lane);
    asm volatile("s_waitcnt vmcnt(4)" ::: "memory");
    SBAR; __builtin_amdgcn_s_barrier(); SBAR;

    for (int t = 0; t < NT; ++t) {
        unsigned short* cur = lds + (t & 1) * 32768;
        unsigned short* nxt = lds + ((t + 1) & 1) * 32768;
        const bool pre = (t + 1 < NT);
        const int k1 = (t + 1) * 64;

        s16x8 b0[4], b1[4], a[4];

        // ---------- ph0: Ks0, acc[0-3] ----------
        #pragma unroll
        for (int nf = 0; nf < 4; ++nf)
            b0[nf] = frag64(cur + 16384, wc * 64 + nf * 16 + r15, kc);
        #pragma unroll
        for (int mf = 0; mf < 4; ++mf)
            a[mf] = frag64(cur, wr * 128 + mf * 16 + r15, kc);
        if (pre) stage_half(Ab, m0, k1, 0, nxt, wave, lane);
        SBAR; __builtin_amdgcn_s_barrier(); SBAR;
        __builtin_amdgcn_s_setprio(1);
        #pragma unroll
        for (int mf = 0; mf < 4; ++mf)
            #pragma unroll
            for (int nf = 0; nf < 4; ++nf)
                acc[mf][nf] = __builtin_amdgcn_mfma_f32_16x16x32_bf16(a[mf], b0[nf], acc[mf][nf], 0, 0, 0);
        __builtin_amdgcn_s_setprio(0);
        SBAR; __builtin_amdgcn_s_barrier(); SBAR;

        // ---------- ph1: Ks0, acc[4-7] ----------
        #pragma unroll
        for (int mf = 0; mf < 4; ++mf)
            a[mf] = frag64(cur, wr * 128 + (mf + 4) * 16 + r15, kc);
        if (pre) stage_half(Bb, n0, k1, 0, nxt + 16384, wave, lane);
        SBAR; __builtin_amdgcn_s_barrier(); SBAR;
        __builtin_amdgcn_s_setprio(1);
        #pragma unroll
        for (int mf = 0; mf < 4; ++mf)
            #pragma unroll
            for (int nf = 0; nf < 4; ++nf)
                acc[mf + 4][nf] = __builtin_amdgcn_mfma_f32_16x16x32_bf16(a[mf], b0[nf], acc[mf + 4][nf], 0, 0, 0);
        __builtin_amdgcn_s_setprio(0);
        SBAR;
        if (pre) { asm volatile("s_waitcnt vmcnt(4)" ::: "memory"); }
        else     { asm volatile("s_waitcnt vmcnt(0)" ::: "memory"); }
        SBAR; __builtin_amdgcn_s_barrier(); SBAR;

        // ---------- ph2: Ks1, acc[0-3] ----------
        #pragma unroll
        for (int nf = 0; nf < 4; ++nf)
            b1[nf] = frag64(cur + 24576, wc * 64 + nf * 16 + r15, kc);
        #pragma unroll
        for (int mf = 0; mf < 4; ++mf)
            a[mf] = frag64(cur + 8192, wr * 128 + mf * 16 + r15, kc);
        if (pre) stage_half(Ab, m0, k1, 1, nxt + 8192, wave, lane);
        SBAR; __builtin_amdgcn_s_barrier(); SBAR;
        __builtin_amdgcn_s_setprio(1);
        #pragma unroll
        for (int mf = 0; mf < 4; ++mf)
            #pragma unroll
            for (int nf = 0; nf < 4; ++nf)
                acc[mf][nf] = __builtin_amdgcn_mfma_f32_16x16x32_bf16(a[mf], b1[nf], acc[mf][nf], 0, 0, 0);
        __builtin_amdgcn_s_setprio(0);
        SBAR; __builtin_amdgcn_s_barrier(); SBAR;

        // ---------- ph3: Ks1, acc[4-7] ----------
        #pragma unroll
        for (int mf = 0; mf < 4; ++mf)
            a[mf] = frag64(cur + 8192, wr * 128 + (mf + 4) * 16 + r15, kc);
        if (pre) stage_half(Bb, n0, k1, 1, nxt + 24576, wave, lane);
        SBAR; __builtin_amdgcn_s_barrier(); SBAR;
        __builtin_amdgcn_s_setprio(1);
        #pragma unroll
        for (int mf = 0; mf < 4; ++mf)
            #pragma unroll
            for (int nf = 0; nf < 4; ++nf)
                acc[mf + 4][nf] = __builtin_amdgcn_mfma_f32_16x16x32_bf16(a[mf], b1[nf], acc[mf + 4][nf], 0, 0, 0);
        __builtin_amdgcn_s_setprio(0);
        SBAR;
        if (pre) { asm volatile("s_waitcnt vmcnt(4)" ::: "memory"); }
        SBAR; __builtin_amdgcn_s_barrier(); SBAR;
    }
}

// ---------------- data GEMM (batched; TOEP variant) ----------------
template<int OUTM, bool TOEP>      // OUTM: 0 = f32 out, 1 = bf16 out
__global__ __launch_bounds__(512, 2) void gemm_big(
    const unsigned short* __restrict__ A, size_t sA,
    const unsigned short* __restrict__ B, size_t sB,
    float* __restrict__ outF, unsigned short* __restrict__ outH, size_t sO,
    const int* __restrict__ idxp, const float* __restrict__ ks)
{
    __shared__ __align__(16) unsigned short lds[2 * 32768];

    const int tid  = threadIdx.x;
    const int lane = tid & 63, wave = tid >> 6;
    const int wr = wave >> 2, wc = wave & 3;        // 2 x 4 wave grid
    const int bz = blockIdx.z;
    int bx = blockIdx.x, by = blockIdx.y;
    if constexpr (TOEP) { int tswap = bx; bx = by; by = tswap; }  // causal balance
    const int m0 = by * 256, n0 = bx * 256;
    const int r15 = lane & 15, kc = lane >> 4;

    const unsigned short* Ab = A + (size_t)bz * sA;
    const unsigned short* Bb = B + (size_t)bz * sB;
    const int NT = TOEP ? 4 * (bx + 1) : 32;

    f32x4 acc[8][4];
    const f32x4 zf = {0.f, 0.f, 0.f, 0.f};
    #pragma unroll
    for (int i = 0; i < 8; ++i)
        #pragma unroll
        for (int j = 0; j < 4; ++j) acc[i][j] = zf;

    kloop64(Ab, Bb, m0, n0, NT, lds, wave, lane, wr, wc, acc);

    float csc[4];
    if constexpr (TOEP) {
        #pragma unroll
        for (int nf = 0; nf < 4; ++nf) {
            int gcol = n0 + wc * 64 + nf * 16 + r15;
            csc[nf] = ks[idxp[bz * L + gcol]];
        }
    }
    #pragma unroll
    for (int mf = 0; mf < 8; ++mf) {
        #pragma unroll
        for (int r = 0; r < 4; ++r) {
            int grow = m0 + wr * 128 + mf * 16 + kc * 4 + r;
            #pragma unroll
            for (int nf = 0; nf < 4; ++nf) {
                float v = acc[mf][nf][r];
                if constexpr (TOEP) v *= csc[nf];
                int gcol = n0 + wc * 64 + nf * 16 + r15;
                size_t o = (size_t)bz * sO + (size_t)grow * 2048 + gcol;
                if constexpr (OUTM == 0) outF[o] = v;
                else                     outH[o] = f2bf(v);
            }
        }
    }
}

// ---------------- precompute GEMMs: up to 3 independent [V,V] per launch ----------------
struct PDesc { const unsigned short* A; const unsigned short* B; float* oF; unsigned short* oH; };

__global__ __launch_bounds__(512, 2) void gemm_pre_big(PDesc d0, PDesc d1, PDesc d2) {
    PDesc d = (blockIdx.z == 0) ? d0 : (blockIdx.z == 1) ? d1 : d2;
    __shared__ __align__(16) unsigned short lds[2 * 32768];

    const int tid  = threadIdx.x;
    const int lane = tid & 63, wave = tid >> 6;
    const int wr = wave >> 2, wc = wave & 3;
    const int m0 = blockIdx.y * 256, n0 = blockIdx.x * 256;
    const int r15 = lane & 15, kc = lane >> 4;

    f32x4 acc[8][4];
    const f32x4 zf = {0.f, 0.f, 0.f, 0.f};
    #pragma unroll
    for (int i = 0; i < 8; ++i)
        #pragma unroll
        for (int j = 0; j < 4; ++j) acc[i][j] = zf;

    kloop64(d.A, d.B, m0, n0, 32, lds, wave, lane, wr, wc, acc);

    const bool isF = (d.oF != nullptr);
    #pragma unroll
    for (int mf = 0; mf < 8; ++mf) {
        #pragma unroll
        for (int r = 0; r < 4; ++r) {
            int grow = m0 + wr * 128 + mf * 16 + kc * 4 + r;
            #pragma unroll
            for (int nf = 0; nf < 4; ++nf) {
                float v = acc[mf][nf][r];
                int gcol = n0 + wc * 64 + nf * 16 + r15;
                size_t o = (size_t)grow * 2048 + gcol;
                if (isF) d.oF[o] = v;
                else     d.oH[o] = f2bf(v);
            }
        }
    }
}

// ---- split-K precompute: z-th K=512 chunk of OUT = A . B^Trows -> f32 partial ----
__global__ __launch_bounds__(512, 2) void gemm_preK(const unsigned short* __restrict__ A,
                                                    const unsigned short* __restrict__ B,
                                                    float* __restrict__ outP) {
    __shared__ __align__(16) unsigned short lds[2 * 32768];

    const int tid  = threadIdx.x;
    const int lane = tid & 63, wave = tid >> 6;
    const int wr = wave >> 2, wc = wave & 3;
    const int m0 = blockIdx.y * 256, n0 = blockIdx.x * 256;
    const int r15 = lane & 15, kc = lane >> 4;
    const int z = blockIdx.z;

    const unsigned short* Ab = A + z * 512;
    const unsigned short* Bb = B + z * 512;
    float* outF = outP + (size_t)z * VV;

    f32x4 acc[8][4];
    const f32x4 zf = {0.f, 0.f, 0.f, 0.f};
    #pragma unroll
    for (int i = 0; i < 8; ++i)
        #pragma unroll
        for (int j = 0; j < 4; ++j) acc[i][j] = zf;

    kloop64(Ab, Bb, m0, n0, 8, lds, wave, lane, wr, wc, acc);

    #pragma unroll
    for (int mf = 0; mf < 8; ++mf) {
        #pragma unroll
        for (int r = 0; r < 4; ++r) {
            int grow = m0 + wr * 128 + mf * 16 + kc * 4 + r;
            #pragma unroll
            for (int nf = 0; nf < 4; ++nf) {
                int gcol = n0 + wc * 64 + nf * 16 + r15;
                outF[(size_t)grow * 2048 + gcol] = acc[mf][nf][r];
            }
        }
    }
}

// reduce 4 f32 partials -> bf16
__global__ __launch_bounds__(256) void reduce4_cast(const float* __restrict__ P,
                                                    unsigned short* __restrict__ H) {
    int i = blockIdx.x * 256 + threadIdx.x;          // float4 index, < VV/4
    const float4* p0 = (const float4*)P;
    const float4* p1 = (const float4*)(P + VV);
    const float4* p2 = (const float4*)(P + 2 * VV);
    const float4* p3 = (const float4*)(P + 3 * VV);
    float4 a = p0[i], b = p1[i], c = p2[i], d = p3[i];
    ushort4 h;
    h.x = f2bf(a.x + b.x + c.x + d.x);
    h.y = f2bf(a.y + b.y + c.y + d.y);
    h.z = f2bf(a.z + b.z + c.z + d.z);
    h.w = f2bf(a.w + b.w + c.w + d.w);
    ((ushort4*)H)[i] = h;
}

// ---------------- prep kernels ----------------

__global__ __launch_bounds__(256) void colsum_atomic(const float* __restrict__ W,
                                                     float* __restrict__ out) {
    int r0 = blockIdx.x * 8;
    int c = threadIdx.x;
    float s[8];
    #pragma unroll
    for (int i = 0; i < 8; ++i) s[i] = 0.f;
    for (int r = 0; r < 8; ++r) {
        const float* row = W + (size_t)(r0 + r) * V;
        #pragma unroll
        for (int i = 0; i < 8; ++i) s[i] += row[c + i * 256];
    }
    #pragma unroll
    for (int i = 0; i < 8; ++i) atomicAdd(&out[c + i * 256], s[i]);
}

__global__ void init_kernel(float* __restrict__ ks0, float* __restrict__ ks1) {
    int i = blockIdx.x * 256 + threadIdx.x;
    if (i < 2048) { ks0[i] = 0.f; ks1[i] = 0.f; }
}

// materialize Toeplitz: TB[n][k] = (k<=n) ? v1[n-k] : 0 (bf16); grid 2048 x 256 thr
__global__ __launch_bounds__(256) void tb_fill(const float* __restrict__ v1,
                                               unsigned short* __restrict__ TBh) {
    int n = blockIdx.x;
    int c0 = threadIdx.x * 8;
    s16x8 hv;
    #pragma unroll
    for (int i = 0; i < 8; ++i) {
        int k = c0 + i;
        float f = (k <= n) ? v1[n - k] : 0.f;
        hv[i] = (short)f2bf(f);
    }
    *(s16x8*)&TBh[(size_t)n * 2048 + c0] = hv;
}

struct TDesc { const float* A; unsigned short* Th; };

// 5 fused transpose+cast: Th[i][j] = bf16(A[j][i]); grid (64,64,5), block (32,8)
__global__ void transpose_cast_multi(TDesc d0, TDesc d1, TDesc d2, TDesc d3, TDesc d4) {
    TDesc d;
    switch (blockIdx.z) {
        case 0: d = d0; break;
        case 1: d = d1; break;
        case 2: d = d2; break;
        case 3: d = d3; break;
        default: d = d4; break;
    }
    __shared__ float tile[32][33];
    int x = blockIdx.x * 32 + threadIdx.x;
    int y0 = blockIdx.y * 32;
    for (int r = threadIdx.y; r < 32; r += 8)
        tile[r][threadIdx.x] = d.A[(size_t)(y0 + r) * V + x];
    __syncthreads();
    int xo = blockIdx.y * 32 + threadIdx.x;
    int yo0 = blockIdx.x * 32;
    for (int r = threadIdx.y; r < 32; r += 8)
        d.Th[(size_t)(yo0 + r) * V + xo] = f2bf(tile[threadIdx.x][r]);
}

// plain cast f32 -> bf16
__global__ __launch_bounds__(256) void cast_kernel(const float* __restrict__ A,
                                                   unsigned short* __restrict__ H,
                                                   int n4) {
    int i = blockIdx.x * 256 + threadIdx.x;
    if (i >= n4) return;
    float4 f = ((const float4*)A)[i];
    ushort4 h;
    h.x = f2bf(f.x); h.y = f2bf(f.y); h.z = f2bf(f.z); h.w = f2bf(f.w);
    ((ushort4*)H)[i] = h;
}

// ---------------- scatter kernels (4 q-rows/block, 64 lanes/row, 4x unrolled) ----------------

__global__ __launch_bounds__(256) void scatterA_kernel(const int* __restrict__ idx,
                                                       const float* __restrict__ G0,
                                                       const float* __restrict__ ks0,
                                                       const float* __restrict__ v0,
                                                       unsigned short* __restrict__ Th) {
    __shared__ float buck[4 * 2048];
    int tid = threadIdx.x;
    const float4 z4 = make_float4(0.f, 0.f, 0.f, 0.f);
    #pragma unroll
    for (int i = 0; i < 8; ++i) ((float4*)buck)[tid + i * 256] = z4;
    __syncthreads();

    int b = blockIdx.y, q0 = blockIdx.x * 4;
    int qr = tid >> 6, lane = tid & 63;
    int q = q0 + qr;
    const int* idxb = idx + b * L;
    int iq = idxb[q];
    float kq = ks0[iq];
    const float* Grow = G0 + (size_t)iq * V;
    float* brow = buck + qr * 2048;

    int k = lane;
    for (; k + 192 <= q; k += 256) {
        int i0 = idxb[k], i1 = idxb[k + 64], i2 = idxb[k + 128], i3 = idxb[k + 192];
        float g0 = Grow[i0], g1 = Grow[i1], g2 = Grow[i2], g3 = Grow[i3];
        float w0 = v0[q - k], w1 = v0[q - k - 64], w2 = v0[q - k - 128], w3 = v0[q - k - 192];
        atomicAdd(&brow[i0], g0 + kq * w0);
        atomicAdd(&brow[i1], g1 + kq * w1);
        atomicAdd(&brow[i2], g2 + kq * w2);
        atomicAdd(&brow[i3], g3 + kq * w3);
    }
    for (; k <= q; k += 64) {
        int ik = idxb[k];
        atomicAdd(&brow[ik], Grow[ik] + kq * v0[q - k]);
    }
    __syncthreads();
    size_t base = ((size_t)b * L + q0) * V;
    #pragma unroll
    for (int it = 0; it < 4; ++it) {
        int i = tid + it * 256;                      // s16x8 index < 1024
        s16x8 hv;
        #pragma unroll
        for (int j = 0; j < 8; ++j) hv[j] = (short)f2bf(buck[i * 8 + j]);
        *(s16x8*)&Th[base + (size_t)i * 8] = hv;
    }
}

// T2 is bf16; row reads coalesced
__global__ __launch_bounds__(256) void scatterC_kernel(const int* __restrict__ idx,
                                                       const unsigned short* __restrict__ T2h,
                                                       unsigned short* __restrict__ Th) {
    __shared__ float buck[4 * 2048];
    int tid = threadIdx.x;
    const float4 z4 = make_float4(0.f, 0.f, 0.f, 0.f);
    #pragma unroll
    for (int i = 0; i < 8; ++i) ((float4*)buck)[tid + i * 256] = z4;
    __syncthreads();

    int b = blockIdx.y, q0 = blockIdx.x * 4;
    int qr = tid >> 6, lane = tid & 63;
    int q = q0 + qr;
    const int* idxb = idx + b * L;
    int iq = idxb[q];
    const unsigned short* Trow = T2h + ((size_t)b * V + iq) * L;
    float* brow = buck + qr * 2048;

    int k = lane;
    for (; k + 192 <= q; k += 256) {
        int i0 = idxb[k], i1 = idxb[k + 64], i2 = idxb[k + 128], i3 = idxb[k + 192];
        float t0 = bf2f(Trow[k]), t1 = bf2f(Trow[k + 64]);
        float t2 = bf2f(Trow[k + 128]), t3 = bf2f(Trow[k + 192]);
        atomicAdd(&brow[i0], t0);
        atomicAdd(&brow[i1], t1);
        atomicAdd(&brow[i2], t2);
        atomicAdd(&brow[i3], t3);
    }
    for (; k <= q; k += 64)
        atomicAdd(&brow[idxb[k]], bf2f(Trow[k]));
    __syncthreads();
    size_t base = ((size_t)b * L + q0) * V;
    #pragma unroll
    for (int it = 0; it < 4; ++it) {
        int i = tid + it * 256;
        s16x8 hv;
        #pragma unroll
        for (int j = 0; j < 8; ++j) hv[j] = (short)f2bf(buck[i * 8 + j]);
        *(s16x8*)&Th[base + (size_t)i * 8] = hv;
    }
}

// ---------------- launcher ----------------

extern "C" void kernel_launch(void* const* d_in, const int* in_sizes, int n_in,
                              void* d_out, int out_size, void* d_ws, size_t ws_size,
                              hipStream_t stream) {
    (void)in_sizes; (void)n_in; (void)out_size; (void)ws_size;
    const int*   idx = (const int*)d_in[0];
    const float* Wq0 = (const float*)d_in[1];
    const float* Wk0 = (const float*)d_in[2];
    const float* Wv0 = (const float*)d_in[3];
    const float* Wk1 = (const float*)d_in[4];
    const float* Wv1 = (const float*)d_in[5];
    const float* Wq2 = (const float*)d_in[6];
    const float* Wk2 = (const float*)d_in[7];
    const float* Wv2 = (const float*)d_in[8];
    const float* v0  = (const float*)d_in[9];
    const float* v1  = (const float*)d_in[10];
    float* out = (float*)d_out;

    char* W = (char*)d_ws;
    const size_t MiB = 1024 * 1024;

    // [0, 64 MiB): PPT (8 MiB) early -> TAh (32 MiB) -> T2h (32 MiB)
    unsigned short* PPT = (unsigned short*)W;
    unsigned short* TAh = (unsigned short*)W;
    unsigned short* T2h = (unsigned short*)W;
    // [8, 72 MiB): R split-K f32 partials (64 MiB, live only between pre1 and reduce)
    float* Rp = (float*)(W + 8 * MiB);
    // [64, 96 MiB): Y1 (Wv0T) + Y2 (Wv1 bf16) early -> Uh -> TCh
    unsigned short* Y1 = (unsigned short*)(W + 64 * MiB);
    unsigned short* Y2 = (unsigned short*)(W + 72 * MiB);
    unsigned short* Uh  = (unsigned short*)(W + 64 * MiB);
    unsigned short* TCh = Uh;
    // [96, 112 MiB): G0 f32
    float* Gf = (float*)(W + 96 * MiB);
    // [112, 120): Y4 = M bf16
    unsigned short* Y4 = (unsigned short*)(W + 112 * MiB);
    // [128+): X slots, 8 MiB each (bf16 [V,V])
    unsigned short* X1 = (unsigned short*)(W + 128 * MiB);  // Wq0T, then R bf16
    unsigned short* X2 = (unsigned short*)(W + 136 * MiB);  // Wk0T, then Wv2 bf16
    unsigned short* X3 = (unsigned short*)(W + 144 * MiB);  // Wq2T, then TBh
    unsigned short* X4 = (unsigned short*)(W + 152 * MiB);  // Wk2T
    unsigned short* TBh = X3;
    float* ks0 = (float*)(W + 192 * MiB);
    float* ks1 = (float*)(W + 192 * MiB + 16 * 1024);

    dim3 blk(256);

    // prep: transposes/casts, column sums
    {
        TDesc t0{Wq0, X1}, t1{Wk0, X2}, t2{Wq2, X3}, t3{Wk2, X4}, t4{Wv0, Y1};
        transpose_cast_multi<<<dim3(64, 64, 5), dim3(32, 8), 0, stream>>>(t0, t1, t2, t3, t4);
    }
    cast_kernel<<<dim3((int)(VV / 4 / 256)), blk, 0, stream>>>(Wv1, Y2, (int)(VV / 4));
    init_kernel<<<dim3(8), blk, 0, stream>>>(ks0, ks1);
    colsum_atomic<<<dim3(256), blk, 0, stream>>>(Wk0, ks0);
    colsum_atomic<<<dim3(256), blk, 0, stream>>>(Wk1, ks1);

    // fused precomputes: G0 = Wq0^T Wk0 (f32), M = Wq2^T Wk2 (bf16), PPT (bf16)
    {
        PDesc dG{X1, X2, Gf, nullptr};
        PDesc dM{X3, X4, nullptr, Y4};
        PDesc dP{Y1, Y2, nullptr, PPT};
        gemm_pre_big<<<dim3(8, 8, 3), dim3(512), 0, stream>>>(dG, dM, dP);
    }
    // TB materialization (X3's Wq2T dead after pre)
    tb_fill<<<dim3(2048), blk, 0, stream>>>(v1, TBh);
    // R = M . PPT via split-K (4 x K=512 f32 partials) -> reduce to X1 bf16
    gemm_preK<<<dim3(8, 8, 4), dim3(512), 0, stream>>>(Y4, PPT, Rp);
    reduce4_cast<<<dim3((int)(VV / 4 / 256)), blk, 0, stream>>>(Rp, X1);

    // scatter A -> TAh (overwrites PPT/Rp head; both dead)
    scatterA_kernel<<<dim3(L / 4, NB), blk, 0, stream>>>(idx, Gf, ks0, v0, TAh);

    // U[b] = R . TA[b]^T -> bf16 Uh
    gemm_big<1, false><<<dim3(8, 8, NB), dim3(512), 0, stream>>>(
        X1, 0, TAh, LV, nullptr, Uh, LV, nullptr, nullptr);

    // T2[b][v,q] = ks1[iq_q] * sum_{k<=q} v1[q-k] * U[b][v,k] -> bf16 T2h (TAh dead)
    gemm_big<1, true><<<dim3(8, 8, NB), dim3(512), 0, stream>>>(
        Uh, LV, TBh, 0, nullptr, T2h, LV, idx, ks1);

    // scatter C -> TCh (overwrites Uh; Uh dead after TOEP)
    scatterC_kernel<<<dim3(L / 4, NB), blk, 0, stream>>>(idx, T2h, TCh);

    // Wv2 -> bf16 X2 (Wk0T dead after pre)
    cast_kernel<<<dim3((int)(VV / 4 / 256)), blk, 0, stream>>>(Wv2, X2, (int)(VV / 4));

    // logits = TC . Wv2rows -> d_out (M = 8192)
    gemm_big<0, false><<<dim3(8, 32, 1), dim3(512), 0, stream>>>(
        TCh, 0, X2, 0, out, nullptr, 0, nullptr, nullptr);
}

// Round 12
// 473.181 us; speedup vs baseline: 1.0523x; 1.0177x over previous
//
#include <hip/hip_runtime.h>

typedef float f32x4 __attribute__((ext_vector_type(4)));
typedef short s16x8 __attribute__((ext_vector_type(8)));

constexpr int L = 2048;
constexpr int V = 2048;
constexpr int NB = 4;
constexpr size_t VV  = (size_t)V * V;      // 4194304
constexpr size_t BLV = (size_t)NB * L * V; // 16777216
constexpr size_t LV  = (size_t)L * V;      // 4194304

// ---------- bf16 helpers (bit-level, RNE) ----------
__device__ __forceinline__ unsigned short f2bf(float f) {
    unsigned u = __float_as_uint(f);
    u = (u + 0x7FFFu + ((u >> 16) & 1u)) >> 16;
    return (unsigned short)u;
}
__device__ __forceinline__ float bf2f(unsigned short s) {
    return __uint_as_float(((unsigned)s) << 16);
}

// ---------- async global->LDS 16B ----------
__device__ __forceinline__ void gload16(const unsigned short* g, unsigned short* l) {
    auto gp = (const __attribute__((address_space(1))) unsigned int*)g;
    auto lp = (__attribute__((address_space(3))) unsigned int*)l;
    __builtin_amdgcn_global_load_lds(gp, lp, 16, 0, 0);
}

#define SBAR __builtin_amdgcn_sched_barrier(0)

// ================= 256x256 bf16 deep-counted pipelined GEMM =================
// BK=32 K-tiles; 3 rotating LDS buffers x 32KB {A 8192 shorts @0, B 8192 @8192}.
// Swizzle within slice: 16B slot = kc ^ ((row>>1)&3)  [proven conflict-free].
// During tile t: stage tile t+2 (A between MFMA clusters, B after) -> issue-to-
// wait distance = 2 tiles. ONE vmcnt(4) + ONE s_barrier per tile; vmcnt(0) only
// at t = NT-2. No sched_barrier pins except the post-barrier data guard.

// stage one 256x32-short K-slice of matrix G into LDS slice base (2 loads/thread)
__device__ __forceinline__ void stage_half(const unsigned short* G, int r0, int k0,
                                           unsigned short* slice, int wave, int lane) {
    int rl = lane >> 2, slot = lane & 3;
    #pragma unroll
    for (int r = 0; r < 2; ++r) {
        int rowl = r * 128 + wave * 16 + rl;
        int colg = k0 + ((slot ^ ((rowl >> 1) & 3)) * 8);
        gload16(G + (size_t)(r0 + rowl) * 2048 + colg,
                slice + (size_t)(r * 128 + wave * 16) * 32);
    }
}

__device__ __forceinline__ s16x8 fragx(const unsigned short* slice, int row, int kc) {
    return *(const s16x8*)&slice[row * 32 + ((kc ^ ((row >> 1) & 3)) * 8)];
}

__device__ __forceinline__ void kloop32(const unsigned short* Ab, const unsigned short* Bb,
                                        int m0, int n0, int NT, unsigned short* lds,
                                        int wave, int lane, int wr, int wc,
                                        f32x4 (&acc)[8][4]) {
    const int r15 = lane & 15, kc = lane >> 4;

    // prologue: stage tiles 0 and 1
    stage_half(Ab, m0, 0,  lds + 0,     wave, lane);
    stage_half(Bb, n0, 0,  lds + 8192,  wave, lane);
    stage_half(Ab, m0, 32, lds + 16384, wave, lane);
    stage_half(Bb, n0, 32, lds + 24576, wave, lane);
    asm volatile("s_waitcnt vmcnt(4)" ::: "memory");
    __builtin_amdgcn_s_barrier();
    SBAR;

    int cb = 0;
    for (int t = 0; t < NT; ++t) {
        const unsigned short* cur = lds + cb * 16384;
        int sb = cb + 2; if (sb >= 3) sb -= 3;
        unsigned short* stg = lds + sb * 16384;
        const bool pre = (t + 2 < NT);
        const int k2 = (t + 2) * 32;

        s16x8 b0[4], a[4], a2[4];
        #pragma unroll
        for (int nf = 0; nf < 4; ++nf)
            b0[nf] = fragx(cur + 8192, wc * 64 + nf * 16 + r15, kc);
        #pragma unroll
        for (int mf = 0; mf < 4; ++mf)
            a[mf] = fragx(cur, wr * 128 + mf * 16 + r15, kc);
        if (pre) stage_half(Ab, m0, k2, stg, wave, lane);
        __builtin_amdgcn_s_setprio(1);
        #pragma unroll
        for (int mf = 0; mf < 4; ++mf)
            #pragma unroll
            for (int nf = 0; nf < 4; ++nf)
                acc[mf][nf] = __builtin_amdgcn_mfma_f32_16x16x32_bf16(a[mf], b0[nf], acc[mf][nf], 0, 0, 0);
        __builtin_amdgcn_s_setprio(0);

        #pragma unroll
        for (int mf = 0; mf < 4; ++mf)
            a2[mf] = fragx(cur, wr * 128 + (mf + 4) * 16 + r15, kc);
        if (pre) stage_half(Bb, n0, k2, stg + 8192, wave, lane);
        __builtin_amdgcn_s_setprio(1);
        #pragma unroll
        for (int mf = 0; mf < 4; ++mf)
            #pragma unroll
            for (int nf = 0; nf < 4; ++nf)
                acc[mf + 4][nf] = __builtin_amdgcn_mfma_f32_16x16x32_bf16(a2[mf], b0[nf], acc[mf + 4][nf], 0, 0, 0);
        __builtin_amdgcn_s_setprio(0);

        if (pre)               { asm volatile("s_waitcnt vmcnt(4)" ::: "memory"); }
        else if (t + 2 == NT)  { asm volatile("s_waitcnt vmcnt(0)" ::: "memory"); }
        __builtin_amdgcn_s_barrier();
        SBAR;
        if (++cb == 3) cb = 0;
    }
}

// ---------------- data GEMM (batched; TOEP variant) ----------------
template<int OUTM, bool TOEP>      // OUTM: 0 = f32 out, 1 = bf16 out
__global__ __launch_bounds__(512, 2) void gemm_big(
    const unsigned short* __restrict__ A, size_t sA,
    const unsigned short* __restrict__ B, size_t sB,
    float* __restrict__ outF, unsigned short* __restrict__ outH, size_t sO,
    const int* __restrict__ idxp, const float* __restrict__ ks)
{
    __shared__ __align__(16) unsigned short lds[3 * 16384];   // 96 KiB

    const int tid  = threadIdx.x;
    const int lane = tid & 63, wave = tid >> 6;
    const int wr = wave >> 2, wc = wave & 3;        // 2 x 4 wave grid
    const int bz = blockIdx.z;
    int bx = blockIdx.x, by = blockIdx.y;
    if constexpr (TOEP) { int tswap = bx; bx = by; by = tswap; }  // causal balance
    const int m0 = by * 256, n0 = bx * 256;
    const int r15 = lane & 15, kc = lane >> 4;

    const unsigned short* Ab = A + (size_t)bz * sA;
    const unsigned short* Bb = B + (size_t)bz * sB;
    const int NT = TOEP ? 8 * (bx + 1) : 64;

    f32x4 acc[8][4];
    const f32x4 zf = {0.f, 0.f, 0.f, 0.f};
    #pragma unroll
    for (int i = 0; i < 8; ++i)
        #pragma unroll
        for (int j = 0; j < 4; ++j) acc[i][j] = zf;

    kloop32(Ab, Bb, m0, n0, NT, lds, wave, lane, wr, wc, acc);

    float csc[4];
    if constexpr (TOEP) {
        #pragma unroll
        for (int nf = 0; nf < 4; ++nf) {
            int gcol = n0 + wc * 64 + nf * 16 + r15;
            csc[nf] = ks[idxp[bz * L + gcol]];
        }
    }
    #pragma unroll
    for (int mf = 0; mf < 8; ++mf) {
        #pragma unroll
        for (int r = 0; r < 4; ++r) {
            int grow = m0 + wr * 128 + mf * 16 + kc * 4 + r;
            #pragma unroll
            for (int nf = 0; nf < 4; ++nf) {
                float v = acc[mf][nf][r];
                if constexpr (TOEP) v *= csc[nf];
                int gcol = n0 + wc * 64 + nf * 16 + r15;
                size_t o = (size_t)bz * sO + (size_t)grow * 2048 + gcol;
                if constexpr (OUTM == 0) outF[o] = v;
                else                     outH[o] = f2bf(v);
            }
        }
    }
}

// ---------------- precompute GEMMs: up to 3 independent [V,V] per launch ----------------
struct PDesc { const unsigned short* A; const unsigned short* B; float* oF; unsigned short* oH; };

__global__ __launch_bounds__(512, 2) void gemm_pre_big(PDesc d0, PDesc d1, PDesc d2) {
    PDesc d = (blockIdx.z == 0) ? d0 : (blockIdx.z == 1) ? d1 : d2;
    __shared__ __align__(16) unsigned short lds[3 * 16384];

    const int tid  = threadIdx.x;
    const int lane = tid & 63, wave = tid >> 6;
    const int wr = wave >> 2, wc = wave & 3;
    const int m0 = blockIdx.y * 256, n0 = blockIdx.x * 256;
    const int r15 = lane & 15, kc = lane >> 4;

    f32x4 acc[8][4];
    const f32x4 zf = {0.f, 0.f, 0.f, 0.f};
    #pragma unroll
    for (int i = 0; i < 8; ++i)
        #pragma unroll
        for (int j = 0; j < 4; ++j) acc[i][j] = zf;

    kloop32(d.A, d.B, m0, n0, 64, lds, wave, lane, wr, wc, acc);

    const bool isF = (d.oF != nullptr);
    #pragma unroll
    for (int mf = 0; mf < 8; ++mf) {
        #pragma unroll
        for (int r = 0; r < 4; ++r) {
            int grow = m0 + wr * 128 + mf * 16 + kc * 4 + r;
            #pragma unroll
            for (int nf = 0; nf < 4; ++nf) {
                float v = acc[mf][nf][r];
                int gcol = n0 + wc * 64 + nf * 16 + r15;
                size_t o = (size_t)grow * 2048 + gcol;
                if (isF) d.oF[o] = v;
                else     d.oH[o] = f2bf(v);
            }
        }
    }
}

// ---- split-K precompute: z-th K=512 chunk of OUT = A . B^Trows -> f32 partial ----
__global__ __launch_bounds__(512, 2) void gemm_preK(const unsigned short* __restrict__ A,
                                                    const unsigned short* __restrict__ B,
                                                    float* __restrict__ outP) {
    __shared__ __align__(16) unsigned short lds[3 * 16384];

    const int tid  = threadIdx.x;
    const int lane = tid & 63, wave = tid >> 6;
    const int wr = wave >> 2, wc = wave & 3;
    const int m0 = blockIdx.y * 256, n0 = blockIdx.x * 256;
    const int r15 = lane & 15, kc = lane >> 4;
    const int z = blockIdx.z;

    const unsigned short* Ab = A + z * 512;
    const unsigned short* Bb = B + z * 512;
    float* outF = outP + (size_t)z * VV;

    f32x4 acc[8][4];
    const f32x4 zf = {0.f, 0.f, 0.f, 0.f};
    #pragma unroll
    for (int i = 0; i < 8; ++i)
        #pragma unroll
        for (int j = 0; j < 4; ++j) acc[i][j] = zf;

    kloop32(Ab, Bb, m0, n0, 16, lds, wave, lane, wr, wc, acc);

    #pragma unroll
    for (int mf = 0; mf < 8; ++mf) {
        #pragma unroll
        for (int r = 0; r < 4; ++r) {
            int grow = m0 + wr * 128 + mf * 16 + kc * 4 + r;
            #pragma unroll
            for (int nf = 0; nf < 4; ++nf) {
                int gcol = n0 + wc * 64 + nf * 16 + r15;
                outF[(size_t)grow * 2048 + gcol] = acc[mf][nf][r];
            }
        }
    }
}

// reduce 4 f32 partials -> bf16
__global__ __launch_bounds__(256) void reduce4_cast(const float* __restrict__ P,
                                                    unsigned short* __restrict__ H) {
    int i = blockIdx.x * 256 + threadIdx.x;          // float4 index, < VV/4
    const float4* p0 = (const float4*)P;
    const float4* p1 = (const float4*)(P + VV);
    const float4* p2 = (const float4*)(P + 2 * VV);
    const float4* p3 = (const float4*)(P + 3 * VV);
    float4 a = p0[i], b = p1[i], c = p2[i], d = p3[i];
    ushort4 h;
    h.x = f2bf(a.x + b.x + c.x + d.x);
    h.y = f2bf(a.y + b.y + c.y + d.y);
    h.z = f2bf(a.z + b.z + c.z + d.z);
    h.w = f2bf(a.w + b.w + c.w + d.w);
    ((ushort4*)H)[i] = h;
}

// ---------------- prep kernels ----------------

__global__ __launch_bounds__(256) void colsum_atomic(const float* __restrict__ W,
                                                     float* __restrict__ out) {
    int r0 = blockIdx.x * 8;
    int c = threadIdx.x;
    float s[8];
    #pragma unroll
    for (int i = 0; i < 8; ++i) s[i] = 0.f;
    for (int r = 0; r < 8; ++r) {
        const float* row = W + (size_t)(r0 + r) * V;
        #pragma unroll
        for (int i = 0; i < 8; ++i) s[i] += row[c + i * 256];
    }
    #pragma unroll
    for (int i = 0; i < 8; ++i) atomicAdd(&out[c + i * 256], s[i]);
}

__global__ void init_kernel(float* __restrict__ ks0, float* __restrict__ ks1) {
    int i = blockIdx.x * 256 + threadIdx.x;
    if (i < 2048) { ks0[i] = 0.f; ks1[i] = 0.f; }
}

// materialize Toeplitz: TB[n][k] = (k<=n) ? v1[n-k] : 0 (bf16); grid 2048 x 256 thr
__global__ __launch_bounds__(256) void tb_fill(const float* __restrict__ v1,
                                               unsigned short* __restrict__ TBh) {
    int n = blockIdx.x;
    int c0 = threadIdx.x * 8;
    s16x8 hv;
    #pragma unroll
    for (int i = 0; i < 8; ++i) {
        int k = c0 + i;
        float f = (k <= n) ? v1[n - k] : 0.f;
        hv[i] = (short)f2bf(f);
    }
    *(s16x8*)&TBh[(size_t)n * 2048 + c0] = hv;
}

struct TDesc { const float* A; unsigned short* Th; };

// 5 fused transpose+cast: Th[i][j] = bf16(A[j][i]); grid (64,64,5), block (32,8)
__global__ void transpose_cast_multi(TDesc d0, TDesc d1, TDesc d2, TDesc d3, TDesc d4) {
    TDesc d;
    switch (blockIdx.z) {
        case 0: d = d0; break;
        case 1: d = d1; break;
        case 2: d = d2; break;
        case 3: d = d3; break;
        default: d = d4; break;
    }
    __shared__ float tile[32][33];
    int x = blockIdx.x * 32 + threadIdx.x;
    int y0 = blockIdx.y * 32;
    for (int r = threadIdx.y; r < 32; r += 8)
        tile[r][threadIdx.x] = d.A[(size_t)(y0 + r) * V + x];
    __syncthreads();
    int xo = blockIdx.y * 32 + threadIdx.x;
    int yo0 = blockIdx.x * 32;
    for (int r = threadIdx.y; r < 32; r += 8)
        d.Th[(size_t)(yo0 + r) * V + xo] = f2bf(tile[threadIdx.x][r]);
}

// plain cast f32 -> bf16
__global__ __launch_bounds__(256) void cast_kernel(const float* __restrict__ A,
                                                   unsigned short* __restrict__ H,
                                                   int n4) {
    int i = blockIdx.x * 256 + threadIdx.x;
    if (i >= n4) return;
    float4 f = ((const float4*)A)[i];
    ushort4 h;
    h.x = f2bf(f.x); h.y = f2bf(f.y); h.z = f2bf(f.z); h.w = f2bf(f.w);
    ((ushort4*)H)[i] = h;
}

// ---------------- scatter kernels (4 q-rows/block, 64 lanes/row, 4x unrolled) ----------------

__global__ __launch_bounds__(256) void scatterA_kernel(const int* __restrict__ idx,
                                                       const float* __restrict__ G0,
                                                       const float* __restrict__ ks0,
                                                       const float* __restrict__ v0,
                                                       unsigned short* __restrict__ Th) {
    __shared__ float buck[4 * 2048];
    int tid = threadIdx.x;
    const float4 z4 = make_float4(0.f, 0.f, 0.f, 0.f);
    #pragma unroll
    for (int i = 0; i < 8; ++i) ((float4*)buck)[tid + i * 256] = z4;
    __syncthreads();

    int b = blockIdx.y, q0 = blockIdx.x * 4;
    int qr = tid >> 6, lane = tid & 63;
    int q = q0 + qr;
    const int* idxb = idx + b * L;
    int iq = idxb[q];
    float kq = ks0[iq];
    const float* Grow = G0 + (size_t)iq * V;
    float* brow = buck + qr * 2048;

    int k = lane;
    for (; k + 192 <= q; k += 256) {
        int i0 = idxb[k], i1 = idxb[k + 64], i2 = idxb[k + 128], i3 = idxb[k + 192];
        float g0 = Grow[i0], g1 = Grow[i1], g2 = Grow[i2], g3 = Grow[i3];
        float w0 = v0[q - k], w1 = v0[q - k - 64], w2 = v0[q - k - 128], w3 = v0[q - k - 192];
        atomicAdd(&brow[i0], g0 + kq * w0);
        atomicAdd(&brow[i1], g1 + kq * w1);
        atomicAdd(&brow[i2], g2 + kq * w2);
        atomicAdd(&brow[i3], g3 + kq * w3);
    }
    for (; k <= q; k += 64) {
        int ik = idxb[k];
        atomicAdd(&brow[ik], Grow[ik] + kq * v0[q - k]);
    }
    __syncthreads();
    size_t base = ((size_t)b * L + q0) * V;
    #pragma unroll
    for (int it = 0; it < 4; ++it) {
        int i = tid + it * 256;                      // s16x8 index < 1024
        s16x8 hv;
        #pragma unroll
        for (int j = 0; j < 8; ++j) hv[j] = (short)f2bf(buck[i * 8 + j]);
        *(s16x8*)&Th[base + (size_t)i * 8] = hv;
    }
}

// T2 is bf16; row reads coalesced
__global__ __launch_bounds__(256) void scatterC_kernel(const int* __restrict__ idx,
                                                       const unsigned short* __restrict__ T2h,
                                                       unsigned short* __restrict__ Th) {
    __shared__ float buck[4 * 2048];
    int tid = threadIdx.x;
    const float4 z4 = make_float4(0.f, 0.f, 0.f, 0.f);
    #pragma unroll
    for (int i = 0; i < 8; ++i) ((float4*)buck)[tid + i * 256] = z4;
    __syncthreads();

    int b = blockIdx.y, q0 = blockIdx.x * 4;
    int qr = tid >> 6, lane = tid & 63;
    int q = q0 + qr;
    const int* idxb = idx + b * L;
    int iq = idxb[q];
    const unsigned short* Trow = T2h + ((size_t)b * V + iq) * L;
    float* brow = buck + qr * 2048;

    int k = lane;
    for (; k + 192 <= q; k += 256) {
        int i0 = idxb[k], i1 = idxb[k + 64], i2 = idxb[k + 128], i3 = idxb[k + 192];
        float t0 = bf2f(Trow[k]), t1 = bf2f(Trow[k + 64]);
        float t2 = bf2f(Trow[k + 128]), t3 = bf2f(Trow[k + 192]);
        atomicAdd(&brow[i0], t0);
        atomicAdd(&brow[i1], t1);
        atomicAdd(&brow[i2], t2);
        atomicAdd(&brow[i3], t3);
    }
    for (; k <= q; k += 64)
        atomicAdd(&brow[idxb[k]], bf2f(Trow[k]));
    __syncthreads();
    size_t base = ((size_t)b * L + q0) * V;
    #pragma unroll
    for (int it = 0; it < 4; ++it) {
        int i = tid + it * 256;
        s16x8 hv;
        #pragma unroll
        for (int j = 0; j < 8; ++j) hv[j] = (short)f2bf(buck[i * 8 + j]);
        *(s16x8*)&Th[base + (size_t)i * 8] = hv;
    }
}

// ---------------- launcher ----------------

extern "C" void kernel_launch(void* const* d_in, const int* in_sizes, int n_in,
                              void* d_out, int out_size, void* d_ws, size_t ws_size,
                              hipStream_t stream) {
    (void)in_sizes; (void)n_in; (void)out_size; (void)ws_size;
    const int*   idx = (const int*)d_in[0];
    const float* Wq0 = (const float*)d_in[1];
    const float* Wk0 = (const float*)d_in[2];
    const float* Wv0 = (const float*)d_in[3];
    const float* Wk1 = (const float*)d_in[4];
    const float* Wv1 = (const float*)d_in[5];
    const float* Wq2 = (const float*)d_in[6];
    const float* Wk2 = (const float*)d_in[7];
    const float* Wv2 = (const float*)d_in[8];
    const float* v0  = (const float*)d_in[9];
    const float* v1  = (const float*)d_in[10];
    float* out = (float*)d_out;

    char* W = (char*)d_ws;
    const size_t MiB = 1024 * 1024;

    // [0, 64 MiB): PPT (8 MiB) early -> TAh (32 MiB) -> T2h (32 MiB)
    unsigned short* PPT = (unsigned short*)W;
    unsigned short* TAh = (unsigned short*)W;
    unsigned short* T2h = (unsigned short*)W;
    // [8, 72 MiB): R split-K f32 partials (64 MiB, live only between preK and reduce)
    float* Rp = (float*)(W + 8 * MiB);
    // [64, 96 MiB): Y1 (Wv0T) + Y2 (Wv1 bf16) early -> Uh -> TCh
    unsigned short* Y1 = (unsigned short*)(W + 64 * MiB);
    unsigned short* Y2 = (unsigned short*)(W + 72 * MiB);
    unsigned short* Uh  = (unsigned short*)(W + 64 * MiB);
    unsigned short* TCh = Uh;
    // [96, 112 MiB): G0 f32
    float* Gf = (float*)(W + 96 * MiB);
    // [112, 120): Y4 = M bf16
    unsigned short* Y4 = (unsigned short*)(W + 112 * MiB);
    // [128+): X slots, 8 MiB each (bf16 [V,V])
    unsigned short* X1 = (unsigned short*)(W + 128 * MiB);  // Wq0T, then R bf16
    unsigned short* X2 = (unsigned short*)(W + 136 * MiB);  // Wk0T, then Wv2 bf16
    unsigned short* X3 = (unsigned short*)(W + 144 * MiB);  // Wq2T, then TBh
    unsigned short* X4 = (unsigned short*)(W + 152 * MiB);  // Wk2T
    unsigned short* TBh = X3;
    float* ks0 = (float*)(W + 192 * MiB);
    float* ks1 = (float*)(W + 192 * MiB + 16 * 1024);

    dim3 blk(256);

    // prep: transposes/casts, column sums
    {
        TDesc t0{Wq0, X1}, t1{Wk0, X2}, t2{Wq2, X3}, t3{Wk2, X4}, t4{Wv0, Y1};
        transpose_cast_multi<<<dim3(64, 64, 5), dim3(32, 8), 0, stream>>>(t0, t1, t2, t3, t4);
    }
    cast_kernel<<<dim3((int)(VV / 4 / 256)), blk, 0, stream>>>(Wv1, Y2, (int)(VV / 4));
    init_kernel<<<dim3(8), blk, 0, stream>>>(ks0, ks1);
    colsum_atomic<<<dim3(256), blk, 0, stream>>>(Wk0, ks0);
    colsum_atomic<<<dim3(256), blk, 0, stream>>>(Wk1, ks1);

    // fused precomputes: G0 = Wq0^T Wk0 (f32), M = Wq2^T Wk2 (bf16), PPT (bf16)
    {
        PDesc dG{X1, X2, Gf, nullptr};
        PDesc dM{X3, X4, nullptr, Y4};
        PDesc dP{Y1, Y2, nullptr, PPT};
        gemm_pre_big<<<dim3(8, 8, 3), dim3(512), 0, stream>>>(dG, dM, dP);
    }
    // TB materialization (X3's Wq2T dead after pre)
    tb_fill<<<dim3(2048), blk, 0, stream>>>(v1, TBh);
    // R = M . PPT via split-K (4 x K=512 f32 partials) -> reduce to X1 bf16
    gemm_preK<<<dim3(8, 8, 4), dim3(512), 0, stream>>>(Y4, PPT, Rp);
    reduce4_cast<<<dim3((int)(VV / 4 / 256)), blk, 0, stream>>>(Rp, X1);

    // scatter A -> TAh (overwrites PPT/Rp head; both dead)
    scatterA_kernel<<<dim3(L / 4, NB), blk, 0, stream>>>(idx, Gf, ks0, v0, TAh);

    // U[b] = R . TA[b]^T -> bf16 Uh
    gemm_big<1, false><<<dim3(8, 8, NB), dim3(512), 0, stream>>>(
        X1, 0, TAh, LV, nullptr, Uh, LV, nullptr, nullptr);

    // T2[b][v,q] = ks1[iq_q] * sum_{k<=q} v1[q-k] * U[b][v,k] -> bf16 T2h (TAh dead)
    gemm_big<1, true><<<dim3(8, 8, NB), dim3(512), 0, stream>>>(
        Uh, LV, TBh, 0, nullptr, T2h, LV, idx, ks1);

    // scatter C -> TCh (overwrites Uh; Uh dead after TOEP)
    scatterC_kernel<<<dim3(L / 4, NB), blk, 0, stream>>>(idx, T2h, TCh);

    // Wv2 -> bf16 X2 (Wk0T dead after pre)
    cast_kernel<<<dim3((int)(VV / 4 / 256)), blk, 0, stream>>>(Wv2, X2, (int)(VV / 4));

    // logits = TC . Wv2rows -> d_out (M = 8192)
    gemm_big<0, false><<<dim3(8, 32, 1), dim3(512), 0, stream>>>(
        TCh, 0, X2, 0, out, nullptr, 0, nullptr, nullptr);
}

// Round 13
// 463.637 us; speedup vs baseline: 1.0739x; 1.0206x over previous
//
#include <hip/hip_runtime.h>

typedef float f32x4 __attribute__((ext_vector_type(4)));
typedef short s16x8 __attribute__((ext_vector_type(8)));

constexpr int L = 2048;
constexpr int V = 2048;
constexpr int NB = 4;
constexpr size_t VV  = (size_t)V * V;      // 4194304
constexpr size_t BLV = (size_t)NB * L * V; // 16777216
constexpr size_t LV  = (size_t)L * V;      // 4194304

// ---------- bf16 helpers (bit-level, RNE) ----------
__device__ __forceinline__ unsigned short f2bf(float f) {
    unsigned u = __float_as_uint(f);
    u = (u + 0x7FFFu + ((u >> 16) & 1u)) >> 16;
    return (unsigned short)u;
}
__device__ __forceinline__ float bf2f(unsigned short s) {
    return __uint_as_float(((unsigned)s) << 16);
}

// ---------- async global->LDS 16B ----------
__device__ __forceinline__ void gload16(const unsigned short* g, unsigned short* l) {
    auto gp = (const __attribute__((address_space(1))) unsigned int*)g;
    auto lp = (__attribute__((address_space(3))) unsigned int*)l;
    __builtin_amdgcn_global_load_lds(gp, lp, 16, 0, 0);
}

#define SBAR __builtin_amdgcn_sched_barrier(0)

// ================= 256x256 bf16 deep-counted pipelined GEMM =================
// BK=32 K-tiles; 3 rotating LDS buffers x 32KB {A 8192 shorts @0, B 8192 @8192}.
// Swizzle within slice: 16B slot = kc ^ ((row>>1)&3)  [proven conflict-free].
// During tile t: stage tile t+2; ONE vmcnt(4) + ONE s_barrier per tile.

__device__ __forceinline__ void stage_half(const unsigned short* G, int r0, int k0,
                                           unsigned short* slice, int wave, int lane) {
    int rl = lane >> 2, slot = lane & 3;
    #pragma unroll
    for (int r = 0; r < 2; ++r) {
        int rowl = r * 128 + wave * 16 + rl;
        int colg = k0 + ((slot ^ ((rowl >> 1) & 3)) * 8);
        gload16(G + (size_t)(r0 + rowl) * 2048 + colg,
                slice + (size_t)(r * 128 + wave * 16) * 32);
    }
}

__device__ __forceinline__ s16x8 fragx(const unsigned short* slice, int row, int kc) {
    return *(const s16x8*)&slice[row * 32 + ((kc ^ ((row >> 1) & 3)) * 8)];
}

// kt0 = starting K-tile index (for split-K); NT = number of K-tiles to process
__device__ __forceinline__ void kloop32(const unsigned short* Ab, const unsigned short* Bb,
                                        int m0, int n0, int kt0, int NT, unsigned short* lds,
                                        int wave, int lane, int wr, int wc,
                                        f32x4 (&acc)[8][4]) {
    const int r15 = lane & 15, kc = lane >> 4;

    // prologue: stage tiles kt0, kt0+1
    stage_half(Ab, m0, kt0 * 32,        lds + 0,     wave, lane);
    stage_half(Bb, n0, kt0 * 32,        lds + 8192,  wave, lane);
    stage_half(Ab, m0, (kt0 + 1) * 32,  lds + 16384, wave, lane);
    stage_half(Bb, n0, (kt0 + 1) * 32,  lds + 24576, wave, lane);
    asm volatile("s_waitcnt vmcnt(4)" ::: "memory");
    __builtin_amdgcn_s_barrier();
    SBAR;

    int cb = 0;
    for (int t = 0; t < NT; ++t) {
        const unsigned short* cur = lds + cb * 16384;
        int sb = cb + 2; if (sb >= 3) sb -= 3;
        unsigned short* stg = lds + sb * 16384;
        const bool pre = (t + 2 < NT);
        const int k2 = (kt0 + t + 2) * 32;

        s16x8 b0[4], a[4], a2[4];
        #pragma unroll
        for (int nf = 0; nf < 4; ++nf)
            b0[nf] = fragx(cur + 8192, wc * 64 + nf * 16 + r15, kc);
        #pragma unroll
        for (int mf = 0; mf < 4; ++mf)
            a[mf] = fragx(cur, wr * 128 + mf * 16 + r15, kc);
        if (pre) stage_half(Ab, m0, k2, stg, wave, lane);
        __builtin_amdgcn_s_setprio(1);
        #pragma unroll
        for (int mf = 0; mf < 4; ++mf)
            #pragma unroll
            for (int nf = 0; nf < 4; ++nf)
                acc[mf][nf] = __builtin_amdgcn_mfma_f32_16x16x32_bf16(a[mf], b0[nf], acc[mf][nf], 0, 0, 0);
        __builtin_amdgcn_s_setprio(0);

        #pragma unroll
        for (int mf = 0; mf < 4; ++mf)
            a2[mf] = fragx(cur, wr * 128 + (mf + 4) * 16 + r15, kc);
        if (pre) stage_half(Bb, n0, k2, stg + 8192, wave, lane);
        __builtin_amdgcn_s_setprio(1);
        #pragma unroll
        for (int mf = 0; mf < 4; ++mf)
            #pragma unroll
            for (int nf = 0; nf < 4; ++nf)
                acc[mf + 4][nf] = __builtin_amdgcn_mfma_f32_16x16x32_bf16(a2[mf], b0[nf], acc[mf + 4][nf], 0, 0, 0);
        __builtin_amdgcn_s_setprio(0);

        if (pre)               { asm volatile("s_waitcnt vmcnt(4)" ::: "memory"); }
        else if (t + 2 == NT)  { asm volatile("s_waitcnt vmcnt(0)" ::: "memory"); }
        __builtin_amdgcn_s_barrier();
        SBAR;
        if (++cb == 3) cb = 0;
    }
}

// XCD-aware chunked swizzle of a flat block id (total % 8 == 0)
__device__ __forceinline__ int xcd_swz(int flat, int total) {
    return (flat & 7) * (total >> 3) + (flat >> 3);
}

// ---------------- data GEMM (batched; TOEP variant with split-K2) ----------------
// TOEP: grid (8,8,8): z = (half<<2)|batch; half computes K-tiles [half*4*(bx+1), +4*(bx+1))
//       and writes to outH + half*BLV. m/n block-swap for causal balance.
template<int OUTM, bool TOEP>      // OUTM: 0 = f32 out, 1 = bf16 out
__global__ __launch_bounds__(512, 2) void gemm_big(
    const unsigned short* __restrict__ A, size_t sA,
    const unsigned short* __restrict__ B, size_t sB,
    float* __restrict__ outF, unsigned short* __restrict__ outH, size_t sO,
    const int* __restrict__ idxp, const float* __restrict__ ks)
{
    __shared__ __align__(16) unsigned short lds[3 * 16384];   // 96 KiB

    const int tid  = threadIdx.x;
    const int lane = tid & 63, wave = tid >> 6;
    const int wr = wave >> 2, wc = wave & 3;        // 2 x 4 wave grid
    const int r15 = lane & 15, kc = lane >> 4;

    int bx, by, bz, half = 0;
    if constexpr (TOEP) {
        bx = blockIdx.y; by = blockIdx.x;           // causal balance swap
        bz = blockIdx.z & 3;
        half = blockIdx.z >> 2;
    } else {
        int gx = gridDim.x, gy = gridDim.y;
        int flat = blockIdx.x + gx * (blockIdx.y + gy * blockIdx.z);
        int total = gx * gy * gridDim.z;
        int n2 = xcd_swz(flat, total);
        bx = n2 % gx; n2 /= gx; by = n2 % gy; bz = n2 / gy;
    }
    const int m0 = by * 256, n0 = bx * 256;

    int kt0 = 0, NT;
    if constexpr (TOEP) {
        int NTh = 4 * (bx + 1);
        kt0 = half * NTh;
        NT = NTh;
    } else {
        NT = 64;
    }

    const unsigned short* Ab = A + (size_t)bz * sA;
    const unsigned short* Bb = B + (size_t)bz * sB;

    f32x4 acc[8][4];
    const f32x4 zf = {0.f, 0.f, 0.f, 0.f};
    #pragma unroll
    for (int i = 0; i < 8; ++i)
        #pragma unroll
        for (int j = 0; j < 4; ++j) acc[i][j] = zf;

    kloop32(Ab, Bb, m0, n0, kt0, NT, lds, wave, lane, wr, wc, acc);

    float csc[4];
    if constexpr (TOEP) {
        #pragma unroll
        for (int nf = 0; nf < 4; ++nf) {
            int gcol = n0 + wc * 64 + nf * 16 + r15;
            csc[nf] = ks[idxp[bz * L + gcol]];
        }
    }
    unsigned short* oH = outH;
    if constexpr (TOEP) oH += (size_t)half * BLV;
    #pragma unroll
    for (int mf = 0; mf < 8; ++mf) {
        #pragma unroll
        for (int r = 0; r < 4; ++r) {
            int grow = m0 + wr * 128 + mf * 16 + kc * 4 + r;
            #pragma unroll
            for (int nf = 0; nf < 4; ++nf) {
                float v = acc[mf][nf][r];
                if constexpr (TOEP) v *= csc[nf];
                int gcol = n0 + wc * 64 + nf * 16 + r15;
                size_t o = (size_t)bz * sO + (size_t)grow * 2048 + gcol;
                if constexpr (OUTM == 0) outF[o] = v;
                else                     oH[o] = f2bf(v);
            }
        }
    }
}

// ---------------- precompute GEMMs: up to 3 independent [V,V] per launch ----------------
struct PDesc { const unsigned short* A; const unsigned short* B; float* oF; unsigned short* oH; };

__global__ __launch_bounds__(512, 2) void gemm_pre_big(PDesc d0, PDesc d1, PDesc d2) {
    __shared__ __align__(16) unsigned short lds[3 * 16384];

    const int tid  = threadIdx.x;
    const int lane = tid & 63, wave = tid >> 6;
    const int wr = wave >> 2, wc = wave & 3;
    const int r15 = lane & 15, kc = lane >> 4;

    int flat = blockIdx.x + 8 * (blockIdx.y + 8 * blockIdx.z);
    int total = 64 * gridDim.z;
    int n2 = xcd_swz(flat, total);
    int bx = n2 & 7; n2 >>= 3;
    int by = n2 & 7; n2 >>= 3;
    PDesc d = (n2 == 0) ? d0 : (n2 == 1) ? d1 : d2;
    const int m0 = by * 256, n0 = bx * 256;

    f32x4 acc[8][4];
    const f32x4 zf = {0.f, 0.f, 0.f, 0.f};
    #pragma unroll
    for (int i = 0; i < 8; ++i)
        #pragma unroll
        for (int j = 0; j < 4; ++j) acc[i][j] = zf;

    kloop32(d.A, d.B, m0, n0, 0, 64, lds, wave, lane, wr, wc, acc);

    const bool isF = (d.oF != nullptr);
    #pragma unroll
    for (int mf = 0; mf < 8; ++mf) {
        #pragma unroll
        for (int r = 0; r < 4; ++r) {
            int grow = m0 + wr * 128 + mf * 16 + kc * 4 + r;
            #pragma unroll
            for (int nf = 0; nf < 4; ++nf) {
                float v = acc[mf][nf][r];
                int gcol = n0 + wc * 64 + nf * 16 + r15;
                size_t o = (size_t)grow * 2048 + gcol;
                if (isF) d.oF[o] = v;
                else     d.oH[o] = f2bf(v);
            }
        }
    }
}

// ---- split-K precompute: z-th K=512 chunk of OUT = A . B^Trows -> f32 partial ----
__global__ __launch_bounds__(512, 2) void gemm_preK(const unsigned short* __restrict__ A,
                                                    const unsigned short* __restrict__ B,
                                                    float* __restrict__ outP) {
    __shared__ __align__(16) unsigned short lds[3 * 16384];

    const int tid  = threadIdx.x;
    const int lane = tid & 63, wave = tid >> 6;
    const int wr = wave >> 2, wc = wave & 3;
    const int r15 = lane & 15, kc = lane >> 4;

    int flat = blockIdx.x + 8 * (blockIdx.y + 8 * blockIdx.z);
    int n2 = xcd_swz(flat, 256);
    int bx = n2 & 7; n2 >>= 3;
    int by = n2 & 7; n2 >>= 3;
    int z = n2;
    const int m0 = by * 256, n0 = bx * 256;

    const unsigned short* Ab = A + z * 512;
    const unsigned short* Bb = B + z * 512;
    float* outF = outP + (size_t)z * VV;

    f32x4 acc[8][4];
    const f32x4 zf = {0.f, 0.f, 0.f, 0.f};
    #pragma unroll
    for (int i = 0; i < 8; ++i)
        #pragma unroll
        for (int j = 0; j < 4; ++j) acc[i][j] = zf;

    kloop32(Ab, Bb, m0, n0, 0, 16, lds, wave, lane, wr, wc, acc);

    #pragma unroll
    for (int mf = 0; mf < 8; ++mf) {
        #pragma unroll
        for (int r = 0; r < 4; ++r) {
            int grow = m0 + wr * 128 + mf * 16 + kc * 4 + r;
            #pragma unroll
            for (int nf = 0; nf < 4; ++nf) {
                int gcol = n0 + wc * 64 + nf * 16 + r15;
                outF[(size_t)grow * 2048 + gcol] = acc[mf][nf][r];
            }
        }
    }
}

// reduce 4 f32 partials -> bf16
__global__ __launch_bounds__(256) void reduce4_cast(const float* __restrict__ P,
                                                    unsigned short* __restrict__ H) {
    int i = blockIdx.x * 256 + threadIdx.x;          // float4 index, < VV/4
    const float4* p0 = (const float4*)P;
    const float4* p1 = (const float4*)(P + VV);
    const float4* p2 = (const float4*)(P + 2 * VV);
    const float4* p3 = (const float4*)(P + 3 * VV);
    float4 a = p0[i], b = p1[i], c = p2[i], d = p3[i];
    ushort4 h;
    h.x = f2bf(a.x + b.x + c.x + d.x);
    h.y = f2bf(a.y + b.y + c.y + d.y);
    h.z = f2bf(a.z + b.z + c.z + d.z);
    h.w = f2bf(a.w + b.w + c.w + d.w);
    ((ushort4*)H)[i] = h;
}

// ---------------- prep kernels ----------------

// fused: both column sums; grid (256, 2)
__global__ __launch_bounds__(256) void colsum2(const float* __restrict__ W0, float* __restrict__ o0,
                                               const float* __restrict__ W1, float* __restrict__ o1) {
    const float* W = blockIdx.y ? W1 : W0;
    float* out = blockIdx.y ? o1 : o0;
    int r0 = blockIdx.x * 8;
    int c = threadIdx.x;
    float s[8];
    #pragma unroll
    for (int i = 0; i < 8; ++i) s[i] = 0.f;
    for (int r = 0; r < 8; ++r) {
        const float* row = W + (size_t)(r0 + r) * V;
        #pragma unroll
        for (int i = 0; i < 8; ++i) s[i] += row[c + i * 256];
    }
    #pragma unroll
    for (int i = 0; i < 8; ++i) atomicAdd(&out[c + i * 256], s[i]);
}

__global__ void init_kernel(float* __restrict__ ks0, float* __restrict__ ks1) {
    int i = blockIdx.x * 256 + threadIdx.x;
    if (i < 2048) { ks0[i] = 0.f; ks1[i] = 0.f; }
}

// materialize Toeplitz: TB[n][k] = (k<=n) ? v1[n-k] : 0 (bf16); grid 2048 x 256 thr
__global__ __launch_bounds__(256) void tb_fill(const float* __restrict__ v1,
                                               unsigned short* __restrict__ TBh) {
    int n = blockIdx.x;
    int c0 = threadIdx.x * 8;
    s16x8 hv;
    #pragma unroll
    for (int i = 0; i < 8; ++i) {
        int k = c0 + i;
        float f = (k <= n) ? v1[n - k] : 0.f;
        hv[i] = (short)f2bf(f);
    }
    *(s16x8*)&TBh[(size_t)n * 2048 + c0] = hv;
}

struct TDesc { const float* A; unsigned short* Th; };

// 5 fused transpose+cast: Th[i][j] = bf16(A[j][i]); grid (64,64,5), block (32,8)
__global__ void transpose_cast_multi(TDesc d0, TDesc d1, TDesc d2, TDesc d3, TDesc d4) {
    TDesc d;
    switch (blockIdx.z) {
        case 0: d = d0; break;
        case 1: d = d1; break;
        case 2: d = d2; break;
        case 3: d = d3; break;
        default: d = d4; break;
    }
    __shared__ float tile[32][33];
    int x = blockIdx.x * 32 + threadIdx.x;
    int y0 = blockIdx.y * 32;
    for (int r = threadIdx.y; r < 32; r += 8)
        tile[r][threadIdx.x] = d.A[(size_t)(y0 + r) * V + x];
    __syncthreads();
    int xo = blockIdx.y * 32 + threadIdx.x;
    int yo0 = blockIdx.x * 32;
    for (int r = threadIdx.y; r < 32; r += 8)
        d.Th[(size_t)(yo0 + r) * V + xo] = f2bf(tile[threadIdx.x][r]);
}

// plain cast f32 -> bf16; two arrays fused via blockIdx.y
__global__ __launch_bounds__(256) void cast2_kernel(const float* __restrict__ A0,
                                                    unsigned short* __restrict__ H0,
                                                    const float* __restrict__ A1,
                                                    unsigned short* __restrict__ H1) {
    const float* A = blockIdx.y ? A1 : A0;
    unsigned short* H = blockIdx.y ? H1 : H0;
    int i = blockIdx.x * 256 + threadIdx.x;
    float4 f = ((const float4*)A)[i];
    ushort4 h;
    h.x = f2bf(f.x); h.y = f2bf(f.y); h.z = f2bf(f.z); h.w = f2bf(f.w);
    ((ushort4*)H)[i] = h;
}

// ---------------- scatter kernels (4 q-rows/block, 64 lanes/row, 4x unrolled) ----------------

__global__ __launch_bounds__(256) void scatterA_kernel(const int* __restrict__ idx,
                                                       const float* __restrict__ G0,
                                                       const float* __restrict__ ks0,
                                                       const float* __restrict__ v0,
                                                       unsigned short* __restrict__ Th) {
    __shared__ float buck[4 * 2048];
    int tid = threadIdx.x;
    const float4 z4 = make_float4(0.f, 0.f, 0.f, 0.f);
    #pragma unroll
    for (int i = 0; i < 8; ++i) ((float4*)buck)[tid + i * 256] = z4;
    __syncthreads();

    int b = blockIdx.y, q0 = blockIdx.x * 4;
    int qr = tid >> 6, lane = tid & 63;
    int q = q0 + qr;
    const int* idxb = idx + b * L;
    int iq = idxb[q];
    float kq = ks0[iq];
    const float* Grow = G0 + (size_t)iq * V;
    float* brow = buck + qr * 2048;

    int k = lane;
    for (; k + 192 <= q; k += 256) {
        int i0 = idxb[k], i1 = idxb[k + 64], i2 = idxb[k + 128], i3 = idxb[k + 192];
        float g0 = Grow[i0], g1 = Grow[i1], g2 = Grow[i2], g3 = Grow[i3];
        float w0 = v0[q - k], w1 = v0[q - k - 64], w2 = v0[q - k - 128], w3 = v0[q - k - 192];
        atomicAdd(&brow[i0], g0 + kq * w0);
        atomicAdd(&brow[i1], g1 + kq * w1);
        atomicAdd(&brow[i2], g2 + kq * w2);
        atomicAdd(&brow[i3], g3 + kq * w3);
    }
    for (; k <= q; k += 64) {
        int ik = idxb[k];
        atomicAdd(&brow[ik], Grow[ik] + kq * v0[q - k]);
    }
    __syncthreads();
    size_t base = ((size_t)b * L + q0) * V;
    #pragma unroll
    for (int it = 0; it < 4; ++it) {
        int i = tid + it * 256;                      // s16x8 index < 1024
        s16x8 hv;
        #pragma unroll
        for (int j = 0; j < 8; ++j) hv[j] = (short)f2bf(buck[i * 8 + j]);
        *(s16x8*)&Th[base + (size_t)i * 8] = hv;
    }
}

// T2 split pair (bf16): gather both halves and add
__global__ __launch_bounds__(256) void scatterC_kernel(const int* __restrict__ idx,
                                                       const unsigned short* __restrict__ T2a,
                                                       const unsigned short* __restrict__ T2b,
                                                       unsigned short* __restrict__ Th) {
    __shared__ float buck[4 * 2048];
    int tid = threadIdx.x;
    const float4 z4 = make_float4(0.f, 0.f, 0.f, 0.f);
    #pragma unroll
    for (int i = 0; i < 8; ++i) ((float4*)buck)[tid + i * 256] = z4;
    __syncthreads();

    int b = blockIdx.y, q0 = blockIdx.x * 4;
    int qr = tid >> 6, lane = tid & 63;
    int q = q0 + qr;
    const int* idxb = idx + b * L;
    int iq = idxb[q];
    size_t roff = ((size_t)b * V + iq) * L;
    const unsigned short* TrA = T2a + roff;
    const unsigned short* TrB = T2b + roff;
    float* brow = buck + qr * 2048;

    int k = lane;
    for (; k + 192 <= q; k += 256) {
        int i0 = idxb[k], i1 = idxb[k + 64], i2 = idxb[k + 128], i3 = idxb[k + 192];
        float t0 = bf2f(TrA[k]) + bf2f(TrB[k]);
        float t1 = bf2f(TrA[k + 64]) + bf2f(TrB[k + 64]);
        float t2 = bf2f(TrA[k + 128]) + bf2f(TrB[k + 128]);
        float t3 = bf2f(TrA[k + 192]) + bf2f(TrB[k + 192]);
        atomicAdd(&brow[i0], t0);
        atomicAdd(&brow[i1], t1);
        atomicAdd(&brow[i2], t2);
        atomicAdd(&brow[i3], t3);
    }
    for (; k <= q; k += 64)
        atomicAdd(&brow[idxb[k]], bf2f(TrA[k]) + bf2f(TrB[k]));
    __syncthreads();
    size_t base = ((size_t)b * L + q0) * V;
    #pragma unroll
    for (int it = 0; it < 4; ++it) {
        int i = tid + it * 256;
        s16x8 hv;
        #pragma unroll
        for (int j = 0; j < 8; ++j) hv[j] = (short)f2bf(buck[i * 8 + j]);
        *(s16x8*)&Th[base + (size_t)i * 8] = hv;
    }
}

// ---------------- launcher ----------------

extern "C" void kernel_launch(void* const* d_in, const int* in_sizes, int n_in,
                              void* d_out, int out_size, void* d_ws, size_t ws_size,
                              hipStream_t stream) {
    (void)in_sizes; (void)n_in; (void)out_size; (void)ws_size;
    const int*   idx = (const int*)d_in[0];
    const float* Wq0 = (const float*)d_in[1];
    const float* Wk0 = (const float*)d_in[2];
    const float* Wv0 = (const float*)d_in[3];
    const float* Wk1 = (const float*)d_in[4];
    const float* Wv1 = (const float*)d_in[5];
    const float* Wq2 = (const float*)d_in[6];
    const float* Wk2 = (const float*)d_in[7];
    const float* Wv2 = (const float*)d_in[8];
    const float* v0  = (const float*)d_in[9];
    const float* v1  = (const float*)d_in[10];
    float* out = (float*)d_out;

    char* W = (char*)d_ws;
    const size_t MiB = 1024 * 1024;

    // [0, 64 MiB): PPT (8 MiB) early -> TAh (32 MiB) -> T2a [0,32) + T2b [32,64)
    unsigned short* PPT = (unsigned short*)W;
    unsigned short* TAh = (unsigned short*)W;
    unsigned short* T2a = (unsigned short*)W;
    unsigned short* T2b = T2a + BLV;                 // +32 MiB
    // [8, 72 MiB): R split-K f32 partials (live preK -> reduce only)
    float* Rp = (float*)(W + 8 * MiB);
    // [64, 96 MiB): Y1 (Wv0T) + Y2 (Wv1 bf16) early -> Uh -> TCh
    unsigned short* Y1 = (unsigned short*)(W + 64 * MiB);
    unsigned short* Y2 = (unsigned short*)(W + 72 * MiB);
    unsigned short* Uh  = (unsigned short*)(W + 64 * MiB);
    unsigned short* TCh = Uh;
    // [96, 112 MiB): G0 f32
    float* Gf = (float*)(W + 96 * MiB);
    // [112, 120): Y4 = M bf16
    unsigned short* Y4 = (unsigned short*)(W + 112 * MiB);
    // [128+): 8 MiB slots
    unsigned short* X1 = (unsigned short*)(W + 128 * MiB);  // Wq0T, then R bf16
    unsigned short* X2 = (unsigned short*)(W + 136 * MiB);  // Wk0T
    unsigned short* X3 = (unsigned short*)(W + 144 * MiB);  // Wq2T
    unsigned short* X4 = (unsigned short*)(W + 152 * MiB);  // Wk2T
    unsigned short* X5 = (unsigned short*)(W + 160 * MiB);  // Wv2 bf16
    unsigned short* TBh = (unsigned short*)(W + 168 * MiB); // Toeplitz bf16
    float* ks0 = (float*)(W + 192 * MiB);
    float* ks1 = (float*)(W + 192 * MiB + 16 * 1024);

    dim3 blk(256);

    // prep: transposes/casts, Toeplitz, column sums (all independent)
    {
        TDesc t0{Wq0, X1}, t1{Wk0, X2}, t2{Wq2, X3}, t3{Wk2, X4}, t4{Wv0, Y1};
        transpose_cast_multi<<<dim3(64, 64, 5), dim3(32, 8), 0, stream>>>(t0, t1, t2, t3, t4);
    }
    cast2_kernel<<<dim3((int)(VV / 4 / 256), 2), blk, 0, stream>>>(Wv1, Y2, Wv2, X5);
    tb_fill<<<dim3(2048), blk, 0, stream>>>(v1, TBh);
    init_kernel<<<dim3(8), blk, 0, stream>>>(ks0, ks1);
    colsum2<<<dim3(256, 2), blk, 0, stream>>>(Wk0, ks0, Wk1, ks1);

    // fused precomputes: G0 = Wq0^T Wk0 (f32), M = Wq2^T Wk2 (bf16), PPT (bf16)
    {
        PDesc dG{X1, X2, Gf, nullptr};
        PDesc dM{X3, X4, nullptr, Y4};
        PDesc dP{Y1, Y2, nullptr, PPT};
        gemm_pre_big<<<dim3(8, 8, 3), dim3(512), 0, stream>>>(dG, dM, dP);
    }
    // R = M . PPT via split-K (4 x K=512 f32 partials) -> reduce to X1 bf16
    gemm_preK<<<dim3(8, 8, 4), dim3(512), 0, stream>>>(Y4, PPT, Rp);
    reduce4_cast<<<dim3((int)(VV / 4 / 256)), blk, 0, stream>>>(Rp, X1);

    // scatter A -> TAh (overwrites PPT/Rp head; both dead)
    scatterA_kernel<<<dim3(L / 4, NB), blk, 0, stream>>>(idx, Gf, ks0, v0, TAh);

    // U[b] = R . TA[b]^T -> bf16 Uh
    gemm_big<1, false><<<dim3(8, 8, NB), dim3(512), 0, stream>>>(
        X1, 0, TAh, LV, nullptr, Uh, LV, nullptr, nullptr);

    // T2[b][v,q] = ks1[iq_q] * sum_{k<=q} v1[q-k] * U[b][v,k]
    // split-K2: halves -> T2a/T2b bf16 (TAh dead; 512 blocks for work-stealing balance)
    gemm_big<1, true><<<dim3(8, 8, 2 * NB), dim3(512), 0, stream>>>(
        Uh, LV, TBh, 0, nullptr, T2a, LV, idx, ks1);

    // scatter C (dual-gather) -> TCh (overwrites Uh)
    scatterC_kernel<<<dim3(L / 4, NB), blk, 0, stream>>>(idx, T2a, T2b, TCh);

    // logits = TC . Wv2rows -> d_out (M = 8192)
    gemm_big<0, false><<<dim3(8, 32, 1), dim3(512), 0, stream>>>(
        TCh, 0, X5, 0, out, nullptr, 0, nullptr, nullptr);
}